// Round 4
// baseline (294.200 us; speedup 1.0000x reference)
//
#include <hip/hip_runtime.h>
#include <hip/hip_bf16.h>

// MultiheadAttention: x[4,2048,1024] fp32 -> out fp32. Internal bf16 MFMA.
// R17: two targeted fixes on top of R16 (305->259 us).
//  attn_k: PV vf reads were the 8.4e6 bank-conflict source (16-lane pass uses
//   only one 8B half of each 16B chunk: bank=chunk*4+qlo*2, qlo uniform per
//   pass). V gets its own LDS, LD=72 (144B rows, 16B aligned), reg-staged
//   (global->reg early, ds_write_b128 after softmax; padding breaks gload_lds).
//   vf banks now 4lc+8kt+2quad -> only free 2-way lc/lc+8 aliasing. No XOR.
//  qkv_gemm_k: epilogue vectorized via MFMA operand swap. z=0/1 computes C^T
//   (mfma(bfr,af)): lane holds 4 consecutive n(=d) per register -> s16x4 8B
//   stores, bias as f32x4. z=2 keeps mfma(af,bfr): lane holds 4 consecutive
//   m(=s) -> s16x4 stores direct to V^T; LDS-transpose epilogue deleted.
//   64 scalar 2B stores/wave -> 16 vector 8B stores/wave.

#define DIM  1024
#define SEQ  2048
#define BATCH 4
#define NH   16
#define HD   64

typedef __bf16 bf16x8 __attribute__((ext_vector_type(8)));
typedef short  s16x4  __attribute__((ext_vector_type(4)));
typedef float  f32x4  __attribute__((ext_vector_type(4)));
typedef unsigned int uint4v __attribute__((ext_vector_type(4)));

static __device__ __forceinline__ f32x4 mfma16(s16x4 a, s16x4 b, f32x4 c) {
    return __builtin_amdgcn_mfma_f32_16x16x16bf16_1k(a, b, c, 0, 0, 0);
}

static __device__ __forceinline__ unsigned short f2b(float f) {
    __bf16 h = (__bf16)f;                      // RNE convert
    return __builtin_bit_cast(unsigned short, h);
}

static __device__ __forceinline__ void load_lds16(const unsigned short* g,
                                                  unsigned short* l) {
    __builtin_amdgcn_global_load_lds(
        (const __attribute__((address_space(1))) void*)g,
        (__attribute__((address_space(3))) void*)l, 16, 0, 0);
}

// ---------------------------------------------------------------------------
// Kernel A: x fp32 -> bf16. 8,388,608 elems -> 4096 blocks.
// ---------------------------------------------------------------------------
__global__ __launch_bounds__(256) void cvt_x_k(const float* __restrict__ x,
                                               unsigned short* __restrict__ xb) {
    size_t i = ((size_t)blockIdx.x * 256 + threadIdx.x) * 8;
    const f32x4* s = (const f32x4*)(x + i);
    f32x4 a0 = s[0], a1 = s[1];
    bf16x8 v;
    for (int j = 0; j < 4; j++) { v[j] = (__bf16)a0[j]; v[4 + j] = (__bf16)a1[j]; }
    *(bf16x8*)(xb + i) = v;
}

// ---------------------------------------------------------------------------
// Kernel 0: Wt[n][k] = bf16(W[k][n]) for z = 0,1,2 (Wq,Wk,Wv). fp32 input.
// ---------------------------------------------------------------------------
__global__ void transpose_w_k(const float* __restrict__ Wq,
                              const float* __restrict__ Wk,
                              const float* __restrict__ Wv,
                              unsigned short* __restrict__ Wt) {
    __shared__ unsigned short t[32][33];
    int z = blockIdx.z;
    const float* W = (z == 0) ? Wq : (z == 1) ? Wk : Wv;
    unsigned short* o = Wt + (size_t)z * DIM * DIM;
    int tx = threadIdx.x;
    int n0 = blockIdx.x * 32, k0 = blockIdx.y * 32;
    for (int j = threadIdx.y; j < 32; j += 8)
        t[j][tx] = f2b(W[(size_t)(k0 + j) * DIM + n0 + tx]);
    __syncthreads();
    for (int j = threadIdx.y; j < 32; j += 8)
        o[(size_t)(n0 + j) * DIM + k0 + tx] = t[tx][j];
}

// ---------------------------------------------------------------------------
// Kernel 1: fused QKV projection. grid (8, 32, 3), 512 thr.
// 256x128 tile, BK=64. global_load_lds + XOR swizzle chunk^=(row&7).
// z=0/1: C^T via mfma(bfr,af) -> vectorized 8B stores. z=2: mfma(af,bfr) ->
// vectorized 8B stores direct to V^T.
// ---------------------------------------------------------------------------
__global__ __launch_bounds__(512) void qkv_gemm_k(
    const unsigned short* __restrict__ xb,
    const unsigned short* __restrict__ WtBase,
    const float* __restrict__ bq,
    const float* __restrict__ bk,
    const float* __restrict__ bv,
    unsigned short* __restrict__ Qo,
    unsigned short* __restrict__ Ko,
    unsigned short* __restrict__ Vto) {
    __shared__ __align__(16) unsigned short As[256 * 64];   // 32 KB, NO pad
    __shared__ __align__(16) unsigned short Bs[128 * 64];   // 16 KB
    int tid = threadIdx.x, wave = tid >> 6, lane = tid & 63;
    int quad = lane >> 4, lc = lane & 15;
    int m0 = blockIdx.y * 256, n0 = blockIdx.x * 128;
    int z = blockIdx.z;
    const unsigned short* Wt = WtBase + (size_t)z * DIM * DIM;
    int wm = (wave >> 1) * 64, wn = (wave & 1) * 64;
    int swzlo = lc & 15 & 7;

    f32x4 acc[4][4] = {};

    if (z != 2) {
        for (int k0 = 0; k0 < DIM; k0 += 64) {
            __syncthreads();
            #pragma unroll
            for (int p = 0; p < 4; p++) {
                int c = tid + p * 512, r = c >> 3, cc = (c & 7) ^ (r & 7);
                load_lds16(xb + (size_t)(m0 + r) * DIM + k0 + cc * 8, &As[c * 8]);
            }
            #pragma unroll
            for (int p = 0; p < 2; p++) {
                int c = tid + p * 512, r = c >> 3, cc = (c & 7) ^ (r & 7);
                load_lds16(Wt + (size_t)(n0 + r) * DIM + k0 + cc * 8, &Bs[c * 8]);
            }
            __syncthreads();
            #pragma unroll
            for (int kk = 0; kk < 2; kk++) {
                int off = ((kk * 4 + quad) ^ swzlo) * 8;
                bf16x8 af[4], bfr[4];
                for (int mt = 0; mt < 4; mt++)
                    af[mt] = *(const bf16x8*)&As[(wm + mt * 16 + lc) * 64 + off];
                for (int nt = 0; nt < 4; nt++)
                    bfr[nt] = *(const bf16x8*)&Bs[(wn + nt * 16 + lc) * 64 + off];
                for (int mt = 0; mt < 4; mt++)
                    for (int nt = 0; nt < 4; nt++)
                        acc[mt][nt] = __builtin_amdgcn_mfma_f32_16x16x32_bf16(
                            bfr[nt], af[mt], acc[mt][nt], 0, 0, 0);   // C^T
            }
        }
        // epilogue: lane holds n = n0+wn+nt*16+quad*4+r (4 consecutive d),
        // m = m0+wm+mt*16+lc. Pack s16x4, 8B stores, dense 512B/instr.
        const float* bias = (z == 0) ? bq : bk;
        float scale = (z == 0) ? 0.18033688011112042f : 1.0f;  // (1/8)*log2(e)
        unsigned short* O = (z == 0) ? Qo : Ko;
        for (int nt = 0; nt < 4; nt++) {
            int n = n0 + wn + nt * 16 + quad * 4;
            f32x4 bv4 = *(const f32x4*)&bias[n];
            int h = n >> 6, d = n & 63;
            for (int mt = 0; mt < 4; mt++) {
                int m = m0 + wm + mt * 16 + lc;
                int b = m >> 11, s = m & 2047;
                s16x4 v4;
                #pragma unroll
                for (int r = 0; r < 4; r++)
                    v4[r] = (short)f2b((acc[mt][nt][r] + bv4[r]) * scale);
                *(s16x4*)&O[((size_t)(b * NH + h) * SEQ + s) * HD + d] = v4;
            }
        }
    } else {
        for (int k0 = 0; k0 < DIM; k0 += 64) {
            __syncthreads();
            #pragma unroll
            for (int p = 0; p < 4; p++) {
                int c = tid + p * 512, r = c >> 3, cc = (c & 7) ^ (r & 7);
                load_lds16(xb + (size_t)(m0 + r) * DIM + k0 + cc * 8, &As[c * 8]);
            }
            #pragma unroll
            for (int p = 0; p < 2; p++) {
                int c = tid + p * 512, r = c >> 3, cc = (c & 7) ^ (r & 7);
                load_lds16(Wt + (size_t)(n0 + r) * DIM + k0 + cc * 8, &Bs[c * 8]);
            }
            __syncthreads();
            #pragma unroll
            for (int kk = 0; kk < 2; kk++) {
                int off = ((kk * 4 + quad) ^ swzlo) * 8;
                bf16x8 af[4], bfr[4];
                for (int mt = 0; mt < 4; mt++)
                    af[mt] = *(const bf16x8*)&As[(wm + mt * 16 + lc) * 64 + off];
                for (int nt = 0; nt < 4; nt++)
                    bfr[nt] = *(const bf16x8*)&Bs[(wn + nt * 16 + lc) * 64 + off];
                for (int mt = 0; mt < 4; mt++)
                    for (int nt = 0; nt < 4; nt++)
                        acc[mt][nt] = __builtin_amdgcn_mfma_f32_16x16x32_bf16(
                            af[mt], bfr[nt], acc[mt][nt], 0, 0, 0);    // C
            }
        }
        // epilogue: lane holds m = m0+wm+mt*16+quad*4+r (4 consecutive s),
        // n = n0+wn+nt*16+lc (= d fixed). 8B stores into V^T[bh][d][s].
        for (int nt = 0; nt < 4; nt++) {
            int n = n0 + wn + nt * 16 + lc;
            float bvl = bv[n];
            int h = n >> 6, d = n & 63;
            for (int mt = 0; mt < 4; mt++) {
                int m = m0 + wm + mt * 16 + quad * 4;
                int b = m >> 11, s = m & 2047;
                s16x4 v4;
                #pragma unroll
                for (int r = 0; r < 4; r++)
                    v4[r] = (short)f2b(acc[mt][nt][r] + bvl);
                *(s16x4*)&Vto[((size_t)(b * NH + h) * HD + d) * SEQ + s] = v4;
            }
        }
    }
}

// ---------------------------------------------------------------------------
// Kernel 2: flash attention (R17). 1024 blocks 1-D, 256 thr (4 waves).
// Block = 128 q; wave owns 32 q (2 groups). XCD-banded grid (bid&7 = XCD).
// K: 2-buf LDS 64x64, XOR-swizzled, gload_lds (linear dest, swizzled src).
// V: 2-buf LDS 64xLDV=72 (144B rows), reg-staged: global->reg early,
//    ds_write_b128 after softmax. vf reads conflict-free (2-way only).
// Score C-layout == K=16 PV B-layout -> P register-resident.
// ---------------------------------------------------------------------------
__global__ __launch_bounds__(256) void attn_k(
    const unsigned short* __restrict__ Q,
    const unsigned short* __restrict__ K,
    const unsigned short* __restrict__ Vt,
    float* __restrict__ out) {
    constexpr int LDV = 72;
    __shared__ __align__(16) unsigned short Ksm[2 * 4096];        // 16 KB
    __shared__ __align__(16) unsigned short Vsm[2 * 64 * LDV];    // 18 KB

    int tid = threadIdx.x, wave = tid >> 6, lane = tid & 63;
    int quad = lane >> 4, lc = lane & 15;
    int swz = lc & 7;
    // XCD-banded decode: bijective bid -> (bh, qt)
    int bid = blockIdx.x;
    int j = bid >> 3;
    int bh = (bid & 7) * 8 + (j >> 4);
    int qt = j & 15;
    int b = bh >> 4, h = bh & 15;
    const unsigned short* Qg = Q + ((size_t)bh * SEQ + qt * 128) * HD;
    const unsigned short* Kg = K + (size_t)bh * SEQ * HD;
    const unsigned short* Vg = Vt + (size_t)bh * HD * SEQ;

    // staging coords (per thread, constant across tiles)
    int sr = tid >> 3, scc = tid & 7;          // rows sr, sr+32; chunk scc
    int kcc = scc ^ (sr & 7);                  // K source-chunk XOR swizzle

    // Q fragments direct from global: B[k=d=ks*32+quad*8+j][n=q=g*16+lc]
    bf16x8 qf0[2], qf1[2];
    {
        const unsigned short* q0 = Qg + (size_t)(wave * 32 + lc) * HD + quad * 8;
        const unsigned short* q1 = q0 + 16 * HD;
        qf0[0] = *(const bf16x8*)q0;  qf0[1] = *(const bf16x8*)(q0 + 32);
        qf1[0] = *(const bf16x8*)q1;  qf1[1] = *(const bf16x8*)(q1 + 32);
    }

    f32x4 o[4][2] = {};   // [dt][g]: O^T[d=dt*16+quad*4+r][q=g*16+lc]
    float rsum0 = 0.0f, rsum1 = 0.0f;

    // prologue: stage tile 0 into buffer 0
    {
        unsigned short* Ks = Ksm;
        unsigned short* Vs = Vsm;
        load_lds16(Kg + (size_t)sr * HD + kcc * 8, &Ks[tid * 8]);
        load_lds16(Kg + (size_t)(sr + 32) * HD + kcc * 8, &Ks[(tid + 256) * 8]);
        uint4v v0 = *(const uint4v*)&Vg[(size_t)sr * SEQ + scc * 8];
        uint4v v1 = *(const uint4v*)&Vg[(size_t)(sr + 32) * SEQ + scc * 8];
        *(uint4v*)&Vs[sr * LDV + scc * 8] = v0;
        *(uint4v*)&Vs[(sr + 32) * LDV + scc * 8] = v1;
    }

    for (int t0 = 0; t0 < SEQ; t0 += 64) {
        int cur = (t0 >> 6) & 1;
        unsigned short* Ks = Ksm + cur * 4096;
        unsigned short* Vs = Vsm + cur * (64 * LDV);
        __syncthreads();   // prev tile fully read + this tile's staging visible

        // issue next-tile staging early (K async to LDS, V to regs)
        uint4v vn0, vn1;
        bool more = (t0 + 64 < SEQ);
        unsigned short* Kn = Ksm + (cur ^ 1) * 4096;
        unsigned short* Vn = Vsm + (cur ^ 1) * (64 * LDV);
        if (more) {
            load_lds16(Kg + (size_t)(t0 + 64 + sr) * HD + kcc * 8, &Kn[tid * 8]);
            load_lds16(Kg + (size_t)(t0 + 96 + sr) * HD + kcc * 8,
                       &Kn[(tid + 256) * 8]);
            vn0 = *(const uint4v*)&Vg[(size_t)sr * SEQ + t0 + 64 + scc * 8];
            vn1 = *(const uint4v*)&Vg[(size_t)(sr + 32) * SEQ + t0 + 64 + scc * 8];
        }

        // QK^T + softmax numerator, per kt (keeps sc lifetime short)
        s16x4 pf[4][2];
        __builtin_amdgcn_s_setprio(1);
        #pragma unroll
        for (int kt = 0; kt < 4; kt++) {
            f32x4 sA = {}, sB = {};
            #pragma unroll
            for (int ks = 0; ks < 2; ks++) {
                bf16x8 kf = *(const bf16x8*)
                    &Ks[(kt * 16 + lc) * 64 + ((ks * 4 + quad) ^ swz) * 8];
                sA = __builtin_amdgcn_mfma_f32_16x16x32_bf16(kf, qf0[ks], sA, 0, 0, 0);
                sB = __builtin_amdgcn_mfma_f32_16x16x32_bf16(kf, qf1[ks], sB, 0, 0, 0);
            }
            #pragma unroll
            for (int r = 0; r < 4; r++) {
                float pa = __builtin_amdgcn_exp2f(sA[r]);
                float pb = __builtin_amdgcn_exp2f(sB[r]);
                rsum0 += pa; rsum1 += pb;
                pf[kt][0][r] = (short)f2b(pa);
                pf[kt][1][r] = (short)f2b(pb);
            }
        }
        __builtin_amdgcn_s_setprio(0);

        // V next-tile LDS write (HBM latency hidden under QK+softmax)
        if (more) {
            *(uint4v*)&Vn[sr * LDV + scc * 8] = vn0;
            *(uint4v*)&Vn[(sr + 32) * LDV + scc * 8] = vn1;
        }

        // PV: o[dt][g] += V^T[d][key] * P[key][q]  (K=16, P register-resident)
        __builtin_amdgcn_s_setprio(1);
        #pragma unroll
        for (int dt = 0; dt < 4; dt++) {
            #pragma unroll
            for (int kt = 0; kt < 4; kt++) {
                s16x4 vf = *(const s16x4*)
                    &Vs[(dt * 16 + lc) * LDV + kt * 16 + quad * 4];
                o[dt][0] = mfma16(vf, pf[kt][0], o[dt][0]);
                o[dt][1] = mfma16(vf, pf[kt][1], o[dt][1]);
            }
        }
        __builtin_amdgcn_s_setprio(0);
    }

    // denominator: reduce partials across quads (same q = lc)
    rsum0 += __shfl_xor(rsum0, 16); rsum0 += __shfl_xor(rsum0, 32);
    rsum1 += __shfl_xor(rsum1, 16); rsum1 += __shfl_xor(rsum1, 32);
    float inv0 = 1.0f / rsum0, inv1 = 1.0f / rsum1;

    // direct stores: row q = qt*128 + wave*32 + g*16 + lc, cols h*64+dt*16+quad*4
    float* o0 = out + ((size_t)b * SEQ + qt * 128 + wave * 32 + lc) * DIM
                + h * HD + quad * 4;
    float* o1 = o0 + (size_t)16 * DIM;
    #pragma unroll
    for (int dt = 0; dt < 4; dt++) {
        f32x4 s0 = o[dt][0]; s0 *= inv0;
        f32x4 s1 = o[dt][1]; s1 *= inv1;
        *(f32x4*)&o0[dt * 16] = s0;
        *(f32x4*)&o1[dt * 16] = s1;
    }
}

// ---------------------------------------------------------------------------
extern "C" void kernel_launch(void* const* d_in, const int* in_sizes, int n_in,
                              void* d_out, int out_size, void* d_ws, size_t ws_size,
                              hipStream_t stream) {
    (void)in_sizes; (void)n_in; (void)out_size; (void)ws_size;
    const float* x  = (const float*)d_in[0];
    const float* Wq = (const float*)d_in[1];
    const float* bq = (const float*)d_in[2];
    const float* Wk = (const float*)d_in[3];
    const float* bk = (const float*)d_in[4];
    const float* Wv = (const float*)d_in[5];
    const float* bv = (const float*)d_in[6];

    char* ws = (char*)d_ws;
    unsigned short* Wt = (unsigned short*)ws;                             // 6 MB
    unsigned short* Qb = (unsigned short*)(ws + (size_t)6 * 1024 * 1024);
    unsigned short* Kb = Qb + (size_t)BATCH * NH * SEQ * HD;
    unsigned short* Vb = Kb + (size_t)BATCH * NH * SEQ * HD;
    unsigned short* xb = (unsigned short*)d_out;  // scratch; attn overwrites

    cvt_x_k<<<dim3(4096), dim3(256), 0, stream>>>(x, xb);
    transpose_w_k<<<dim3(32, 32, 3), dim3(32, 8), 0, stream>>>(Wq, Wk, Wv, Wt);
    qkv_gemm_k<<<dim3(8, 32, 3), dim3(512), 0, stream>>>(xb, Wt, bq, bk, bv, Qb, Kb, Vb);
    attn_k<<<dim3(1024), dim3(256), 0, stream>>>(Qb, Kb, Vb, (float*)d_out);
}

// Round 5
// 268.121 us; speedup vs baseline: 1.0973x; 1.0973x over previous
//
#include <hip/hip_runtime.h>
#include <hip/hip_bf16.h>

// MultiheadAttention: x[4,2048,1024] fp32 -> out fp32. Internal bf16 MFMA.
// R18: revert R17 (both halves regressed; conflict count bit-identical across
// V layouts falsified the vf theory; qkv 8B-stride-128B stores decoalesced).
// qkv_gemm_k = R16 verbatim. attn_k = R16 structure but 8 waves x 16 q:
//   R16 was grid-capped at 4 blocks/CU (1024 blocks, Occupancy 24.5%) with
//   only 4 waves/SIMD - latency-bound, MfmaUtil 41%. 512 thr/block keeps
//   grid+LDS identical but doubles waves/CU (target 8/SIMD if VGPR<=64;
//   per-wave state halves: o[4]+qf[2]+pf[4] ~= 32 VGPRs of state).
//   Staging: 1 gload_lds per thread per array (512 thr = 8KB tile / 16B).

#define DIM  1024
#define SEQ  2048
#define BATCH 4
#define NH   16
#define HD   64

typedef __bf16 bf16x8 __attribute__((ext_vector_type(8)));
typedef short  s16x4  __attribute__((ext_vector_type(4)));
typedef float  f32x4  __attribute__((ext_vector_type(4)));
typedef unsigned int uint4v __attribute__((ext_vector_type(4)));

static __device__ __forceinline__ f32x4 mfma16(s16x4 a, s16x4 b, f32x4 c) {
    return __builtin_amdgcn_mfma_f32_16x16x16bf16_1k(a, b, c, 0, 0, 0);
}

static __device__ __forceinline__ unsigned short f2b(float f) {
    __bf16 h = (__bf16)f;                      // RNE convert
    return __builtin_bit_cast(unsigned short, h);
}

static __device__ __forceinline__ void load_lds16(const unsigned short* g,
                                                  unsigned short* l) {
    __builtin_amdgcn_global_load_lds(
        (const __attribute__((address_space(1))) void*)g,
        (__attribute__((address_space(3))) void*)l, 16, 0, 0);
}

// ---------------------------------------------------------------------------
// Kernel A: x fp32 -> bf16. 8,388,608 elems -> 4096 blocks.
// ---------------------------------------------------------------------------
__global__ __launch_bounds__(256) void cvt_x_k(const float* __restrict__ x,
                                               unsigned short* __restrict__ xb) {
    size_t i = ((size_t)blockIdx.x * 256 + threadIdx.x) * 8;
    const f32x4* s = (const f32x4*)(x + i);
    f32x4 a0 = s[0], a1 = s[1];
    bf16x8 v;
    for (int j = 0; j < 4; j++) { v[j] = (__bf16)a0[j]; v[4 + j] = (__bf16)a1[j]; }
    *(bf16x8*)(xb + i) = v;
}

// ---------------------------------------------------------------------------
// Kernel 0: Wt[n][k] = bf16(W[k][n]) for z = 0,1,2 (Wq,Wk,Wv). fp32 input.
// ---------------------------------------------------------------------------
__global__ void transpose_w_k(const float* __restrict__ Wq,
                              const float* __restrict__ Wk,
                              const float* __restrict__ Wv,
                              unsigned short* __restrict__ Wt) {
    __shared__ unsigned short t[32][33];
    int z = blockIdx.z;
    const float* W = (z == 0) ? Wq : (z == 1) ? Wk : Wv;
    unsigned short* o = Wt + (size_t)z * DIM * DIM;
    int tx = threadIdx.x;
    int n0 = blockIdx.x * 32, k0 = blockIdx.y * 32;
    for (int j = threadIdx.y; j < 32; j += 8)
        t[j][tx] = f2b(W[(size_t)(k0 + j) * DIM + n0 + tx]);
    __syncthreads();
    for (int j = threadIdx.y; j < 32; j += 8)
        o[(size_t)(n0 + j) * DIM + k0 + tx] = t[tx][j];
}

// ---------------------------------------------------------------------------
// Kernel 1: fused QKV projection (R16 verbatim). grid (8, 32, 3), 512 thr.
// 256x128 tile, BK=64. global_load_lds + XOR swizzle chunk^=(row&7).
// z=0 -> Q scaled log2e/8, z=1 -> K, z=2 -> V^T via per-wave LDS transpose.
// ---------------------------------------------------------------------------
__global__ __launch_bounds__(512) void qkv_gemm_k(
    const unsigned short* __restrict__ xb,
    const unsigned short* __restrict__ WtBase,
    const float* __restrict__ bq,
    const float* __restrict__ bk,
    const float* __restrict__ bv,
    unsigned short* __restrict__ Qo,
    unsigned short* __restrict__ Ko,
    unsigned short* __restrict__ Vto) {
    __shared__ __align__(16) unsigned short As[256 * 64];   // 32 KB, NO pad
    __shared__ __align__(16) unsigned short Bs[128 * 64];   // 16 KB
    int tid = threadIdx.x, wave = tid >> 6, lane = tid & 63;
    int quad = lane >> 4, lc = lane & 15;
    int m0 = blockIdx.y * 256, n0 = blockIdx.x * 128;
    int z = blockIdx.z;
    const unsigned short* Wt = WtBase + (size_t)z * DIM * DIM;
    int wm = (wave >> 1) * 64, wn = (wave & 1) * 64;
    int swzlo = lc & 7;

    f32x4 acc[4][4] = {};

    for (int k0 = 0; k0 < DIM; k0 += 64) {
        __syncthreads();
        #pragma unroll
        for (int p = 0; p < 4; p++) {
            int c = tid + p * 512, r = c >> 3, cc = (c & 7) ^ (r & 7);
            load_lds16(xb + (size_t)(m0 + r) * DIM + k0 + cc * 8, &As[c * 8]);
        }
        #pragma unroll
        for (int p = 0; p < 2; p++) {
            int c = tid + p * 512, r = c >> 3, cc = (c & 7) ^ (r & 7);
            load_lds16(Wt + (size_t)(n0 + r) * DIM + k0 + cc * 8, &Bs[c * 8]);
        }
        __syncthreads();
        #pragma unroll
        for (int kk = 0; kk < 2; kk++) {
            int off = ((kk * 4 + quad) ^ swzlo) * 8;
            bf16x8 af[4], bfr[4];
            for (int mt = 0; mt < 4; mt++)
                af[mt] = *(const bf16x8*)&As[(wm + mt * 16 + lc) * 64 + off];
            for (int nt = 0; nt < 4; nt++)
                bfr[nt] = *(const bf16x8*)&Bs[(wn + nt * 16 + lc) * 64 + off];
            for (int mt = 0; mt < 4; mt++)
                for (int nt = 0; nt < 4; nt++)
                    acc[mt][nt] = __builtin_amdgcn_mfma_f32_16x16x32_bf16(
                        af[mt], bfr[nt], acc[mt][nt], 0, 0, 0);
        }
    }

    const float* bias = (z == 0) ? bq : (z == 1) ? bk : bv;
    float scale = (z == 0) ? 0.18033688011112042f : 1.0f;  // (1/8)*log2(e)

    if (z != 2) {
        for (int nt = 0; nt < 4; nt++) {
            int n = n0 + wn + nt * 16 + lc;
            float bvl = bias[n];
            int h = n >> 6, d = n & 63;
            for (int mt = 0; mt < 4; mt++) {
                for (int r = 0; r < 4; r++) {
                    int m = m0 + wm + mt * 16 + quad * 4 + r;
                    int b = m >> 11, s = m & 2047;
                    unsigned short ub = f2b((acc[mt][nt][r] + bvl) * scale);
                    if (z == 0)
                        Qo[((size_t)(b * NH + h) * SEQ + s) * HD + d] = ub;
                    else
                        Ko[((size_t)(b * NH + h) * SEQ + s) * HD + d] = ub;
                }
            }
        }
    } else {
        // V^T: per-wave LDS transpose (16 m x 64 n slices), coalesced stores.
        __syncthreads();
        unsigned short* T = As + wave * 1024;
        int h = (n0 + wn) >> 6;
        int d = lane;
        for (int mt = 0; mt < 4; mt++) {
            for (int nt = 0; nt < 4; nt++) {
                int n = n0 + wn + nt * 16 + lc;
                float bvl = bias[n];
                s16x4 v4;
                for (int r = 0; r < 4; r++)
                    v4[r] = (short)f2b(acc[mt][nt][r] + bvl);
                *(s16x4*)&T[(nt * 16 + lc) * 16 + quad * 4] = v4;
            }
            int s_base = m0 + wm + mt * 16;
            int b = s_base >> 11, sl = s_base & 2047;
            unsigned short* dst =
                Vto + ((size_t)(b * NH + h) * HD + d) * SEQ + sl;
            uint4v t0 = *(const uint4v*)&T[d * 16];
            uint4v t1 = *(const uint4v*)&T[d * 16 + 8];
            *(uint4v*)&dst[0] = t0;
            *(uint4v*)&dst[8] = t1;
        }
    }
}

// ---------------------------------------------------------------------------
// Kernel 2: flash attention (R18). 1024 blocks 1-D, 512 thr (8 waves).
// Block = 128 q; wave owns 16 q (w*16 + lc). XCD-banded grid (bid&7 = XCD).
// K/V double-buffered LDS 64x64 each, XOR-swizzled, gload_lds-staged
// (linear dest, swizzled per-lane source). Q fragments direct from global.
// Score C-layout == K=16 PV B-layout -> P register-resident.
// ---------------------------------------------------------------------------
__global__ __launch_bounds__(512) void attn_k(
    const unsigned short* __restrict__ Q,
    const unsigned short* __restrict__ K,
    const unsigned short* __restrict__ Vt,
    float* __restrict__ out) {
    // 2 buffers x (K 64x64 + V^T 64x64) shorts = 2 x 16 KB
    __shared__ __align__(16) unsigned short KV[2 * 8192];

    int tid = threadIdx.x, wave = tid >> 6, lane = tid & 63;
    int quad = lane >> 4, lc = lane & 15;
    int swz = lc & 7;
    // XCD-banded decode: bijective bid -> (bh, qt)
    int bid = blockIdx.x;
    int j = bid >> 3;
    int bh = (bid & 7) * 8 + (j >> 4);
    int qt = j & 15;
    int b = bh >> 4, h = bh & 15;
    const unsigned short* Qg = Q + ((size_t)bh * SEQ + qt * 128) * HD;
    const unsigned short* Kg = K + (size_t)bh * SEQ * HD;
    const unsigned short* Vg = Vt + (size_t)bh * HD * SEQ;

    // staging coords: 512 threads cover one 64x8-chunk tile exactly
    int sr = tid >> 3, scc = tid & 7;          // row sr, chunk scc
    int kcc = scc ^ (sr & 7);                  // XOR source-chunk swizzle

    // Q fragments direct from global: B[k=d=ks*32+quad*8+j][n=q=w*16+lc]
    bf16x8 qf[2];
    {
        const unsigned short* q0 = Qg + (size_t)(wave * 16 + lc) * HD + quad * 8;
        qf[0] = *(const bf16x8*)q0;
        qf[1] = *(const bf16x8*)(q0 + 32);
    }

    f32x4 o[4] = {};   // [dt]: O^T[d=dt*16+quad*4+r][q=w*16+lc]
    float rsum = 0.0f;

    // prologue: stage tile 0 into buffer 0 (linear dest, swizzled source)
    {
        unsigned short* Ks = KV;
        unsigned short* Vs = KV + 4096;
        load_lds16(Kg + (size_t)sr * HD + kcc * 8, &Ks[tid * 8]);
        load_lds16(Vg + (size_t)sr * SEQ + kcc * 8, &Vs[tid * 8]);
    }

    for (int t0 = 0; t0 < SEQ; t0 += 64) {
        int cur = (t0 >> 6) & 1;
        unsigned short* Ks = KV + cur * 8192;
        unsigned short* Vs = Ks + 4096;
        __syncthreads();   // drains prior gload_lds (compiler vmcnt) + hazard

        if (t0 + 64 < SEQ) {   // stage next tile into other buffer
            unsigned short* Kn = KV + (cur ^ 1) * 8192;
            unsigned short* Vn = Kn + 4096;
            load_lds16(Kg + (size_t)(t0 + 64 + sr) * HD + kcc * 8, &Kn[tid * 8]);
            load_lds16(Vg + (size_t)sr * SEQ + (t0 + 64) + kcc * 8, &Vn[tid * 8]);
        }

        // QK^T + softmax numerator, per kt (keeps sc lifetime short)
        s16x4 pf[4];
        __builtin_amdgcn_s_setprio(1);
        #pragma unroll
        for (int kt = 0; kt < 4; kt++) {
            f32x4 sA = {};
            #pragma unroll
            for (int ks = 0; ks < 2; ks++) {
                bf16x8 kf = *(const bf16x8*)
                    &Ks[(kt * 16 + lc) * 64 + ((ks * 4 + quad) ^ swz) * 8];
                sA = __builtin_amdgcn_mfma_f32_16x16x32_bf16(kf, qf[ks], sA, 0, 0, 0);
            }
            #pragma unroll
            for (int r = 0; r < 4; r++) {
                float pa = __builtin_amdgcn_exp2f(sA[r]);
                rsum += pa;
                pf[kt][r] = (short)f2b(pa);
            }
        }

        // PV: o[dt] += V^T[d][key] * P[key][q]  (K=16, P register-resident)
        #pragma unroll
        for (int dt = 0; dt < 4; dt++) {
            #pragma unroll
            for (int kt = 0; kt < 4; kt++) {
                s16x4 vf = *(const s16x4*)
                    &Vs[(dt * 16 + lc) * 64 +
                        ((2 * kt + (quad >> 1)) ^ swz) * 8 + (quad & 1) * 4];
                o[dt] = mfma16(vf, pf[kt], o[dt]);
            }
        }
        __builtin_amdgcn_s_setprio(0);
    }

    // denominator: reduce partials across quads (same q = lc)
    rsum += __shfl_xor(rsum, 16);
    rsum += __shfl_xor(rsum, 32);
    float inv = 1.0f / rsum;

    // direct stores: row q = qt*128 + wave*16 + lc, cols h*64 + dt*16 + quad*4
    float* orow = out + ((size_t)b * SEQ + qt * 128 + wave * 16 + lc) * DIM
                  + h * HD + quad * 4;
    #pragma unroll
    for (int dt = 0; dt < 4; dt++) {
        f32x4 s = o[dt];
        s *= inv;
        *(f32x4*)&orow[dt * 16] = s;
    }
}

// ---------------------------------------------------------------------------
extern "C" void kernel_launch(void* const* d_in, const int* in_sizes, int n_in,
                              void* d_out, int out_size, void* d_ws, size_t ws_size,
                              hipStream_t stream) {
    (void)in_sizes; (void)n_in; (void)out_size; (void)ws_size;
    const float* x  = (const float*)d_in[0];
    const float* Wq = (const float*)d_in[1];
    const float* bq = (const float*)d_in[2];
    const float* Wk = (const float*)d_in[3];
    const float* bk = (const float*)d_in[4];
    const float* Wv = (const float*)d_in[5];
    const float* bv = (const float*)d_in[6];

    char* ws = (char*)d_ws;
    unsigned short* Wt = (unsigned short*)ws;                             // 6 MB
    unsigned short* Qb = (unsigned short*)(ws + (size_t)6 * 1024 * 1024);
    unsigned short* Kb = Qb + (size_t)BATCH * NH * SEQ * HD;
    unsigned short* Vb = Kb + (size_t)BATCH * NH * SEQ * HD;
    unsigned short* xb = (unsigned short*)d_out;  // scratch; attn overwrites

    cvt_x_k<<<dim3(4096), dim3(256), 0, stream>>>(x, xb);
    transpose_w_k<<<dim3(32, 32, 3), dim3(32, 8), 0, stream>>>(Wq, Wk, Wv, Wt);
    qkv_gemm_k<<<dim3(8, 32, 3), dim3(512), 0, stream>>>(xb, Wt, bq, bk, bv, Qb, Kb, Vb);
    attn_k<<<dim3(1024), dim3(512), 0, stream>>>(Qb, Kb, Vb, (float*)d_out);
}

// Round 6
// 249.331 us; speedup vs baseline: 1.1800x; 1.0754x over previous
//
#include <hip/hip_runtime.h>
#include <hip/hip_bf16.h>

// MultiheadAttention: x[4,2048,1024] fp32 -> out fp32. Internal bf16 MFMA.
// R19: attn_k LDS-traffic halving. R18 post-mortem: LDS pipe ~96% saturated
// (each wave reads full 16KB K+V tile; 16 q/wave -> 4.3 GB total LDS reads;
// occupancy doubling was neutral because the LDS pipe was the wall).
//   - 32 q/wave (2 groups, R16's per-wave shape, VGPR ~76) x 8 waves
//     = 256 q/block; grid 512 (XCD-banded, 8 bh per XCD). LDS reads 2.15 GB.
//   - swizzle s(row) = (row ^ (row>>3)) & 7 replaces (row&7): rows lc/lc+8
//     now hit disjoint bank sets on kf b128 reads (was 2-way on every read,
//     the invariant 64 conflict-cyc/wave-tile). Staging source + LDS read
//     use the same involution (both-sides rule).
// qkv_gemm_k / cvt_x_k / transpose_w_k unchanged (R16).

#define DIM  1024
#define SEQ  2048
#define BATCH 4
#define NH   16
#define HD   64

typedef __bf16 bf16x8 __attribute__((ext_vector_type(8)));
typedef short  s16x4  __attribute__((ext_vector_type(4)));
typedef float  f32x4  __attribute__((ext_vector_type(4)));
typedef unsigned int uint4v __attribute__((ext_vector_type(4)));

static __device__ __forceinline__ f32x4 mfma16(s16x4 a, s16x4 b, f32x4 c) {
    return __builtin_amdgcn_mfma_f32_16x16x16bf16_1k(a, b, c, 0, 0, 0);
}

static __device__ __forceinline__ unsigned short f2b(float f) {
    __bf16 h = (__bf16)f;                      // RNE convert
    return __builtin_bit_cast(unsigned short, h);
}

static __device__ __forceinline__ void load_lds16(const unsigned short* g,
                                                  unsigned short* l) {
    __builtin_amdgcn_global_load_lds(
        (const __attribute__((address_space(1))) void*)g,
        (__attribute__((address_space(3))) void*)l, 16, 0, 0);
}

// ---------------------------------------------------------------------------
// Kernel A: x fp32 -> bf16. 8,388,608 elems -> 4096 blocks.
// ---------------------------------------------------------------------------
__global__ __launch_bounds__(256) void cvt_x_k(const float* __restrict__ x,
                                               unsigned short* __restrict__ xb) {
    size_t i = ((size_t)blockIdx.x * 256 + threadIdx.x) * 8;
    const f32x4* s = (const f32x4*)(x + i);
    f32x4 a0 = s[0], a1 = s[1];
    bf16x8 v;
    for (int j = 0; j < 4; j++) { v[j] = (__bf16)a0[j]; v[4 + j] = (__bf16)a1[j]; }
    *(bf16x8*)(xb + i) = v;
}

// ---------------------------------------------------------------------------
// Kernel 0: Wt[n][k] = bf16(W[k][n]) for z = 0,1,2 (Wq,Wk,Wv). fp32 input.
// ---------------------------------------------------------------------------
__global__ void transpose_w_k(const float* __restrict__ Wq,
                              const float* __restrict__ Wk,
                              const float* __restrict__ Wv,
                              unsigned short* __restrict__ Wt) {
    __shared__ unsigned short t[32][33];
    int z = blockIdx.z;
    const float* W = (z == 0) ? Wq : (z == 1) ? Wk : Wv;
    unsigned short* o = Wt + (size_t)z * DIM * DIM;
    int tx = threadIdx.x;
    int n0 = blockIdx.x * 32, k0 = blockIdx.y * 32;
    for (int j = threadIdx.y; j < 32; j += 8)
        t[j][tx] = f2b(W[(size_t)(k0 + j) * DIM + n0 + tx]);
    __syncthreads();
    for (int j = threadIdx.y; j < 32; j += 8)
        o[(size_t)(n0 + j) * DIM + k0 + tx] = t[tx][j];
}

// ---------------------------------------------------------------------------
// Kernel 1: fused QKV projection (R16 verbatim). grid (8, 32, 3), 512 thr.
// 256x128 tile, BK=64. global_load_lds + XOR swizzle chunk^=(row&7).
// z=0 -> Q scaled log2e/8, z=1 -> K, z=2 -> V^T via per-wave LDS transpose.
// ---------------------------------------------------------------------------
__global__ __launch_bounds__(512) void qkv_gemm_k(
    const unsigned short* __restrict__ xb,
    const unsigned short* __restrict__ WtBase,
    const float* __restrict__ bq,
    const float* __restrict__ bk,
    const float* __restrict__ bv,
    unsigned short* __restrict__ Qo,
    unsigned short* __restrict__ Ko,
    unsigned short* __restrict__ Vto) {
    __shared__ __align__(16) unsigned short As[256 * 64];   // 32 KB, NO pad
    __shared__ __align__(16) unsigned short Bs[128 * 64];   // 16 KB
    int tid = threadIdx.x, wave = tid >> 6, lane = tid & 63;
    int quad = lane >> 4, lc = lane & 15;
    int m0 = blockIdx.y * 256, n0 = blockIdx.x * 128;
    int z = blockIdx.z;
    const unsigned short* Wt = WtBase + (size_t)z * DIM * DIM;
    int wm = (wave >> 1) * 64, wn = (wave & 1) * 64;
    int swzlo = lc & 7;

    f32x4 acc[4][4] = {};

    for (int k0 = 0; k0 < DIM; k0 += 64) {
        __syncthreads();
        #pragma unroll
        for (int p = 0; p < 4; p++) {
            int c = tid + p * 512, r = c >> 3, cc = (c & 7) ^ (r & 7);
            load_lds16(xb + (size_t)(m0 + r) * DIM + k0 + cc * 8, &As[c * 8]);
        }
        #pragma unroll
        for (int p = 0; p < 2; p++) {
            int c = tid + p * 512, r = c >> 3, cc = (c & 7) ^ (r & 7);
            load_lds16(Wt + (size_t)(n0 + r) * DIM + k0 + cc * 8, &Bs[c * 8]);
        }
        __syncthreads();
        #pragma unroll
        for (int kk = 0; kk < 2; kk++) {
            int off = ((kk * 4 + quad) ^ swzlo) * 8;
            bf16x8 af[4], bfr[4];
            for (int mt = 0; mt < 4; mt++)
                af[mt] = *(const bf16x8*)&As[(wm + mt * 16 + lc) * 64 + off];
            for (int nt = 0; nt < 4; nt++)
                bfr[nt] = *(const bf16x8*)&Bs[(wn + nt * 16 + lc) * 64 + off];
            for (int mt = 0; mt < 4; mt++)
                for (int nt = 0; nt < 4; nt++)
                    acc[mt][nt] = __builtin_amdgcn_mfma_f32_16x16x32_bf16(
                        af[mt], bfr[nt], acc[mt][nt], 0, 0, 0);
        }
    }

    const float* bias = (z == 0) ? bq : (z == 1) ? bk : bv;
    float scale = (z == 0) ? 0.18033688011112042f : 1.0f;  // (1/8)*log2(e)

    if (z != 2) {
        for (int nt = 0; nt < 4; nt++) {
            int n = n0 + wn + nt * 16 + lc;
            float bvl = bias[n];
            int h = n >> 6, d = n & 63;
            for (int mt = 0; mt < 4; mt++) {
                for (int r = 0; r < 4; r++) {
                    int m = m0 + wm + mt * 16 + quad * 4 + r;
                    int b = m >> 11, s = m & 2047;
                    unsigned short ub = f2b((acc[mt][nt][r] + bvl) * scale);
                    if (z == 0)
                        Qo[((size_t)(b * NH + h) * SEQ + s) * HD + d] = ub;
                    else
                        Ko[((size_t)(b * NH + h) * SEQ + s) * HD + d] = ub;
                }
            }
        }
    } else {
        // V^T: per-wave LDS transpose (16 m x 64 n slices), coalesced stores.
        __syncthreads();
        unsigned short* T = As + wave * 1024;
        int h = (n0 + wn) >> 6;
        int d = lane;
        for (int mt = 0; mt < 4; mt++) {
            for (int nt = 0; nt < 4; nt++) {
                int n = n0 + wn + nt * 16 + lc;
                float bvl = bias[n];
                s16x4 v4;
                for (int r = 0; r < 4; r++)
                    v4[r] = (short)f2b(acc[mt][nt][r] + bvl);
                *(s16x4*)&T[(nt * 16 + lc) * 16 + quad * 4] = v4;
            }
            int s_base = m0 + wm + mt * 16;
            int b = s_base >> 11, sl = s_base & 2047;
            unsigned short* dst =
                Vto + ((size_t)(b * NH + h) * HD + d) * SEQ + sl;
            uint4v t0 = *(const uint4v*)&T[d * 16];
            uint4v t1 = *(const uint4v*)&T[d * 16 + 8];
            *(uint4v*)&dst[0] = t0;
            *(uint4v*)&dst[8] = t1;
        }
    }
}

// ---------------------------------------------------------------------------
// Kernel 2: flash attention (R19). 512 blocks 1-D, 512 thr (8 waves).
// Block = 256 q; wave owns 32 q (2 groups: w*32 + g*16 + lc).
// XCD-banded grid (bid&7 = XCD, 8 bh per XCD band).
// K/V double-buffered LDS 64x64 each; swizzle s(row)=(row^(row>>3))&7
// applied to source chunk on staging and to chunk select on reads.
// Q fragments direct from global. Score C-layout == K=16 PV B-layout.
// ---------------------------------------------------------------------------
__global__ __launch_bounds__(512) void attn_k(
    const unsigned short* __restrict__ Q,
    const unsigned short* __restrict__ K,
    const unsigned short* __restrict__ Vt,
    float* __restrict__ out) {
    // 2 buffers x (K 64x64 + V^T 64x64) shorts = 2 x 16 KB
    __shared__ __align__(16) unsigned short KV[2 * 8192];

    int tid = threadIdx.x, wave = tid >> 6, lane = tid & 63;
    int quad = lane >> 4, lc = lane & 15;
    int lc7 = lc & 7, lcb = lc >> 3;
    // XCD-banded decode: bijective bid -> (bh, qt); 512 blocks, 8 qt per bh
    int bid = blockIdx.x;
    int j = bid >> 3;
    int bh = (bid & 7) * 8 + (j >> 3);
    int qt = j & 7;
    int b = bh >> 4, h = bh & 15;
    const unsigned short* Qg = Q + ((size_t)bh * SEQ + qt * 256) * HD;
    const unsigned short* Kg = K + (size_t)bh * SEQ * HD;
    const unsigned short* Vg = Vt + (size_t)bh * HD * SEQ;

    // staging coords: 512 threads cover one 64x8-chunk tile exactly.
    // LDS dest linear: row sr, chunk scc. Source chunk = scc ^ s(sr),
    // s(row) = (row ^ (row>>3)) & 7  (rows 8 apart -> different chunk sets).
    int sr = tid >> 3, scc = tid & 7;
    int kcc = scc ^ ((sr ^ (sr >> 3)) & 7);

    // Q fragments direct from global: B[k=d=ks*32+quad*8+j][n=q=g*16+lc]
    bf16x8 qf0[2], qf1[2];
    {
        const unsigned short* q0 = Qg + (size_t)(wave * 32 + lc) * HD + quad * 8;
        const unsigned short* q1 = q0 + 16 * HD;
        qf0[0] = *(const bf16x8*)q0;  qf0[1] = *(const bf16x8*)(q0 + 32);
        qf1[0] = *(const bf16x8*)q1;  qf1[1] = *(const bf16x8*)(q1 + 32);
    }

    f32x4 o[4][2] = {};   // [dt][g]: O^T[d=dt*16+quad*4+r][q=g*16+lc]
    float rsum0 = 0.0f, rsum1 = 0.0f;

    // prologue: stage tile 0 into buffer 0 (linear dest, swizzled source)
    {
        unsigned short* Ks = KV;
        unsigned short* Vs = KV + 4096;
        load_lds16(Kg + (size_t)sr * HD + kcc * 8, &Ks[tid * 8]);
        load_lds16(Vg + (size_t)sr * SEQ + kcc * 8, &Vs[tid * 8]);
    }

    for (int t0 = 0; t0 < SEQ; t0 += 64) {
        int cur = (t0 >> 6) & 1;
        unsigned short* Ks = KV + cur * 8192;
        unsigned short* Vs = Ks + 4096;
        __syncthreads();   // drains prior gload_lds (compiler vmcnt) + hazard

        if (t0 + 64 < SEQ) {   // stage next tile into other buffer
            unsigned short* Kn = KV + (cur ^ 1) * 8192;
            unsigned short* Vn = Kn + 4096;
            load_lds16(Kg + (size_t)(t0 + 64 + sr) * HD + kcc * 8, &Kn[tid * 8]);
            load_lds16(Vg + (size_t)sr * SEQ + (t0 + 64) + kcc * 8, &Vn[tid * 8]);
        }

        // QK^T + softmax numerator, per kt (keeps sc lifetime short)
        s16x4 pf[4][2];
        __builtin_amdgcn_s_setprio(1);
        #pragma unroll
        for (int kt = 0; kt < 4; kt++) {
            // row = kt*16 + lc -> s(row) = lc7 ^ ((2*kt + lcb) & 7)
            int sk = lc7 ^ ((2 * kt + lcb) & 7);
            f32x4 sA = {}, sB = {};
            #pragma unroll
            for (int ks = 0; ks < 2; ks++) {
                bf16x8 kf = *(const bf16x8*)
                    &Ks[(kt * 16 + lc) * 64 + ((ks * 4 + quad) ^ sk) * 8];
                sA = __builtin_amdgcn_mfma_f32_16x16x32_bf16(kf, qf0[ks], sA, 0, 0, 0);
                sB = __builtin_amdgcn_mfma_f32_16x16x32_bf16(kf, qf1[ks], sB, 0, 0, 0);
            }
            #pragma unroll
            for (int r = 0; r < 4; r++) {
                float pa = __builtin_amdgcn_exp2f(sA[r]);
                float pb = __builtin_amdgcn_exp2f(sB[r]);
                rsum0 += pa; rsum1 += pb;
                pf[kt][0][r] = (short)f2b(pa);
                pf[kt][1][r] = (short)f2b(pb);
            }
        }

        // PV: o[dt][g] += V^T[d][key] * P[key][q]  (K=16, P register-resident)
        #pragma unroll
        for (int dt = 0; dt < 4; dt++) {
            // row = dt*16 + lc -> s(row) = lc7 ^ ((2*dt + lcb) & 7)
            int sv = lc7 ^ ((2 * dt + lcb) & 7);
            #pragma unroll
            for (int kt = 0; kt < 4; kt++) {
                s16x4 vf = *(const s16x4*)
                    &Vs[(dt * 16 + lc) * 64 +
                        ((2 * kt + (quad >> 1)) ^ sv) * 8 + (quad & 1) * 4];
                o[dt][0] = mfma16(vf, pf[kt][0], o[dt][0]);
                o[dt][1] = mfma16(vf, pf[kt][1], o[dt][1]);
            }
        }
        __builtin_amdgcn_s_setprio(0);
    }

    // denominator: reduce partials across quads (same q = lc)
    rsum0 += __shfl_xor(rsum0, 16); rsum0 += __shfl_xor(rsum0, 32);
    rsum1 += __shfl_xor(rsum1, 16); rsum1 += __shfl_xor(rsum1, 32);
    float inv0 = 1.0f / rsum0, inv1 = 1.0f / rsum1;

    // direct stores: row q = qt*256 + wave*32 + g*16 + lc, cols h*64+dt*16+quad*4
    float* o0 = out + ((size_t)b * SEQ + qt * 256 + wave * 32 + lc) * DIM
                + h * HD + quad * 4;
    float* o1 = o0 + (size_t)16 * DIM;
    #pragma unroll
    for (int dt = 0; dt < 4; dt++) {
        f32x4 s0 = o[dt][0]; s0 *= inv0;
        f32x4 s1 = o[dt][1]; s1 *= inv1;
        *(f32x4*)&o0[dt * 16] = s0;
        *(f32x4*)&o1[dt * 16] = s1;
    }
}

// ---------------------------------------------------------------------------
extern "C" void kernel_launch(void* const* d_in, const int* in_sizes, int n_in,
                              void* d_out, int out_size, void* d_ws, size_t ws_size,
                              hipStream_t stream) {
    (void)in_sizes; (void)n_in; (void)out_size; (void)ws_size;
    const float* x  = (const float*)d_in[0];
    const float* Wq = (const float*)d_in[1];
    const float* bq = (const float*)d_in[2];
    const float* Wk = (const float*)d_in[3];
    const float* bk = (const float*)d_in[4];
    const float* Wv = (const float*)d_in[5];
    const float* bv = (const float*)d_in[6];

    char* ws = (char*)d_ws;
    unsigned short* Wt = (unsigned short*)ws;                             // 6 MB
    unsigned short* Qb = (unsigned short*)(ws + (size_t)6 * 1024 * 1024);
    unsigned short* Kb = Qb + (size_t)BATCH * NH * SEQ * HD;
    unsigned short* Vb = Kb + (size_t)BATCH * NH * SEQ * HD;
    unsigned short* xb = (unsigned short*)d_out;  // scratch; attn overwrites

    cvt_x_k<<<dim3(4096), dim3(256), 0, stream>>>(x, xb);
    transpose_w_k<<<dim3(32, 32, 3), dim3(32, 8), 0, stream>>>(Wq, Wk, Wv, Wt);
    qkv_gemm_k<<<dim3(8, 32, 3), dim3(512), 0, stream>>>(xb, Wt, bq, bk, bv, Qb, Kb, Vb);
    attn_k<<<dim3(512), dim3(512), 0, stream>>>(Qb, Kb, Vb, (float*)d_out);
}

// Round 8
// 242.554 us; speedup vs baseline: 1.2129x; 1.0279x over previous
//
#include <hip/hip_runtime.h>
#include <hip/hip_bf16.h>

// MultiheadAttention: x[4,2048,1024] fp32 -> out fp32. Internal bf16 MFMA.
// R20 (resubmit; prior run died to container infra, no signal).
//  attn_k: rsum moved from VALU to MFMA pipe. With A=ones, mfma16 gives
//   D[m][q] = sum_k P[k][q] for every m -> persistent racc[2] accumulates the
//   softmax denominator across all kt/tiles; racc[g][0] is the full sum for
//   q = g*16+lc on every lane. Deletes 64 v_add/wave-tile + final shfl_xor
//   reduce (VALU was 51% busy vs MFMA 43.6% -> rebalance toward MFMA).
//   Denominator now sums the same bf16-rounded p as the PV numerator.
//  qkv_gemm_k: XCD-panel clustering. 1D grid 768, bid&7 = XCD; XCD x owns
//   m-panels p === x (mod 8) -> the 24 blocks (8 n x 3 z) sharing a 512KB
//   A-panel co-reside on one XCD (A from L2, was 8x HBM/L3 refetch).
// R19 attn structure otherwise verbatim (s(row) swizzle, 32q/wave, 8 waves).

#define DIM  1024
#define SEQ  2048
#define BATCH 4
#define NH   16
#define HD   64

typedef __bf16 bf16x8 __attribute__((ext_vector_type(8)));
typedef short  s16x4  __attribute__((ext_vector_type(4)));
typedef float  f32x4  __attribute__((ext_vector_type(4)));
typedef unsigned int uint4v __attribute__((ext_vector_type(4)));

static __device__ __forceinline__ f32x4 mfma16(s16x4 a, s16x4 b, f32x4 c) {
    return __builtin_amdgcn_mfma_f32_16x16x16bf16_1k(a, b, c, 0, 0, 0);
}

static __device__ __forceinline__ unsigned short f2b(float f) {
    __bf16 h = (__bf16)f;                      // RNE convert
    return __builtin_bit_cast(unsigned short, h);
}

static __device__ __forceinline__ void load_lds16(const unsigned short* g,
                                                  unsigned short* l) {
    __builtin_amdgcn_global_load_lds(
        (const __attribute__((address_space(1))) void*)g,
        (__attribute__((address_space(3))) void*)l, 16, 0, 0);
}

// ---------------------------------------------------------------------------
// Kernel A: x fp32 -> bf16. 8,388,608 elems -> 4096 blocks.
// ---------------------------------------------------------------------------
__global__ __launch_bounds__(256) void cvt_x_k(const float* __restrict__ x,
                                               unsigned short* __restrict__ xb) {
    size_t i = ((size_t)blockIdx.x * 256 + threadIdx.x) * 8;
    const f32x4* s = (const f32x4*)(x + i);
    f32x4 a0 = s[0], a1 = s[1];
    bf16x8 v;
    for (int j = 0; j < 4; j++) { v[j] = (__bf16)a0[j]; v[4 + j] = (__bf16)a1[j]; }
    *(bf16x8*)(xb + i) = v;
}

// ---------------------------------------------------------------------------
// Kernel 0: Wt[n][k] = bf16(W[k][n]) for z = 0,1,2 (Wq,Wk,Wv). fp32 input.
// ---------------------------------------------------------------------------
__global__ void transpose_w_k(const float* __restrict__ Wq,
                              const float* __restrict__ Wk,
                              const float* __restrict__ Wv,
                              unsigned short* __restrict__ Wt) {
    __shared__ unsigned short t[32][33];
    int z = blockIdx.z;
    const float* W = (z == 0) ? Wq : (z == 1) ? Wk : Wv;
    unsigned short* o = Wt + (size_t)z * DIM * DIM;
    int tx = threadIdx.x;
    int n0 = blockIdx.x * 32, k0 = blockIdx.y * 32;
    for (int j = threadIdx.y; j < 32; j += 8)
        t[j][tx] = f2b(W[(size_t)(k0 + j) * DIM + n0 + tx]);
    __syncthreads();
    for (int j = threadIdx.y; j < 32; j += 8)
        o[(size_t)(n0 + j) * DIM + k0 + tx] = t[tx][j];
}

// ---------------------------------------------------------------------------
// Kernel 1: fused QKV projection. 1D grid 768, 512 thr.
// 256x128 tile, BK=64. global_load_lds + XOR swizzle chunk^=(row&7).
// XCD-panel clustering: bid&7 = XCD; p = (slot/24)*8 + xcd; i = slot%24
// encodes (z, nx). 24 blocks sharing an A-panel co-reside on one XCD.
// z=0 -> Q scaled log2e/8, z=1 -> K, z=2 -> V^T via per-wave LDS transpose.
// ---------------------------------------------------------------------------
__global__ __launch_bounds__(512) void qkv_gemm_k(
    const unsigned short* __restrict__ xb,
    const unsigned short* __restrict__ WtBase,
    const float* __restrict__ bq,
    const float* __restrict__ bk,
    const float* __restrict__ bv,
    unsigned short* __restrict__ Qo,
    unsigned short* __restrict__ Ko,
    unsigned short* __restrict__ Vto) {
    __shared__ __align__(16) unsigned short As[256 * 64];   // 32 KB, NO pad
    __shared__ __align__(16) unsigned short Bs[128 * 64];   // 16 KB
    int tid = threadIdx.x, wave = tid >> 6, lane = tid & 63;
    int quad = lane >> 4, lc = lane & 15;
    // XCD-panel decode
    int bid = blockIdx.x;
    int xcd = bid & 7, slot = bid >> 3;
    int pp = slot / 24, i = slot - pp * 24;
    int p = pp * 8 + xcd;
    int z = i >> 3, nx = i & 7;
    int m0 = p * 256, n0 = nx * 128;
    const unsigned short* Wt = WtBase + (size_t)z * DIM * DIM;
    int wm = (wave >> 1) * 64, wn = (wave & 1) * 64;
    int swzlo = lc & 7;

    f32x4 acc[4][4] = {};

    for (int k0 = 0; k0 < DIM; k0 += 64) {
        __syncthreads();
        #pragma unroll
        for (int pI = 0; pI < 4; pI++) {
            int c = tid + pI * 512, r = c >> 3, cc = (c & 7) ^ (r & 7);
            load_lds16(xb + (size_t)(m0 + r) * DIM + k0 + cc * 8, &As[c * 8]);
        }
        #pragma unroll
        for (int pI = 0; pI < 2; pI++) {
            int c = tid + pI * 512, r = c >> 3, cc = (c & 7) ^ (r & 7);
            load_lds16(Wt + (size_t)(n0 + r) * DIM + k0 + cc * 8, &Bs[c * 8]);
        }
        __syncthreads();
        #pragma unroll
        for (int kk = 0; kk < 2; kk++) {
            int off = ((kk * 4 + quad) ^ swzlo) * 8;
            bf16x8 af[4], bfr[4];
            for (int mt = 0; mt < 4; mt++)
                af[mt] = *(const bf16x8*)&As[(wm + mt * 16 + lc) * 64 + off];
            for (int nt = 0; nt < 4; nt++)
                bfr[nt] = *(const bf16x8*)&Bs[(wn + nt * 16 + lc) * 64 + off];
            for (int mt = 0; mt < 4; mt++)
                for (int nt = 0; nt < 4; nt++)
                    acc[mt][nt] = __builtin_amdgcn_mfma_f32_16x16x32_bf16(
                        af[mt], bfr[nt], acc[mt][nt], 0, 0, 0);
        }
    }

    const float* bias = (z == 0) ? bq : (z == 1) ? bk : bv;
    float scale = (z == 0) ? 0.18033688011112042f : 1.0f;  // (1/8)*log2(e)

    if (z != 2) {
        for (int nt = 0; nt < 4; nt++) {
            int n = n0 + wn + nt * 16 + lc;
            float bvl = bias[n];
            int h = n >> 6, d = n & 63;
            for (int mt = 0; mt < 4; mt++) {
                for (int r = 0; r < 4; r++) {
                    int m = m0 + wm + mt * 16 + quad * 4 + r;
                    int b = m >> 11, s = m & 2047;
                    unsigned short ub = f2b((acc[mt][nt][r] + bvl) * scale);
                    if (z == 0)
                        Qo[((size_t)(b * NH + h) * SEQ + s) * HD + d] = ub;
                    else
                        Ko[((size_t)(b * NH + h) * SEQ + s) * HD + d] = ub;
                }
            }
        }
    } else {
        // V^T: per-wave LDS transpose (16 m x 64 n slices), coalesced stores.
        __syncthreads();
        unsigned short* T = As + wave * 1024;
        int h = (n0 + wn) >> 6;
        int d = lane;
        for (int mt = 0; mt < 4; mt++) {
            for (int nt = 0; nt < 4; nt++) {
                int n = n0 + wn + nt * 16 + lc;
                float bvl = bias[n];
                s16x4 v4;
                for (int r = 0; r < 4; r++)
                    v4[r] = (short)f2b(acc[mt][nt][r] + bvl);
                *(s16x4*)&T[(nt * 16 + lc) * 16 + quad * 4] = v4;
            }
            int s_base = m0 + wm + mt * 16;
            int b = s_base >> 11, sl = s_base & 2047;
            unsigned short* dst =
                Vto + ((size_t)(b * NH + h) * HD + d) * SEQ + sl;
            uint4v t0 = *(const uint4v*)&T[d * 16];
            uint4v t1 = *(const uint4v*)&T[d * 16 + 8];
            *(uint4v*)&dst[0] = t0;
            *(uint4v*)&dst[8] = t1;
        }
    }
}

// ---------------------------------------------------------------------------
// Kernel 2: flash attention (R20). 512 blocks 1-D, 512 thr (8 waves).
// Block = 256 q; wave owns 32 q (2 groups: w*32 + g*16 + lc).
// XCD-banded grid (bid&7 = XCD, 8 bh per XCD band).
// K/V double-buffered LDS 64x64 each; swizzle s(row)=(row^(row>>3))&7.
// Softmax denominator via mfma16(ones, pf, racc) - no VALU adds, no shfl.
// ---------------------------------------------------------------------------
__global__ __launch_bounds__(512) void attn_k(
    const unsigned short* __restrict__ Q,
    const unsigned short* __restrict__ K,
    const unsigned short* __restrict__ Vt,
    float* __restrict__ out) {
    // 2 buffers x (K 64x64 + V^T 64x64) shorts = 2 x 16 KB
    __shared__ __align__(16) unsigned short KV[2 * 8192];

    int tid = threadIdx.x, wave = tid >> 6, lane = tid & 63;
    int quad = lane >> 4, lc = lane & 15;
    int lc7 = lc & 7, lcb = lc >> 3;
    // XCD-banded decode: bijective bid -> (bh, qt); 512 blocks, 8 qt per bh
    int bid = blockIdx.x;
    int j = bid >> 3;
    int bh = (bid & 7) * 8 + (j >> 3);
    int qt = j & 7;
    int b = bh >> 4, h = bh & 15;
    const unsigned short* Qg = Q + ((size_t)bh * SEQ + qt * 256) * HD;
    const unsigned short* Kg = K + (size_t)bh * SEQ * HD;
    const unsigned short* Vg = Vt + (size_t)bh * HD * SEQ;

    // staging coords: 512 threads cover one 64x8-chunk tile exactly.
    int sr = tid >> 3, scc = tid & 7;
    int kcc = scc ^ ((sr ^ (sr >> 3)) & 7);

    // Q fragments direct from global: B[k=d=ks*32+quad*8+j][n=q=g*16+lc]
    bf16x8 qf0[2], qf1[2];
    {
        const unsigned short* q0 = Qg + (size_t)(wave * 32 + lc) * HD + quad * 8;
        const unsigned short* q1 = q0 + 16 * HD;
        qf0[0] = *(const bf16x8*)q0;  qf0[1] = *(const bf16x8*)(q0 + 32);
        qf1[0] = *(const bf16x8*)q1;  qf1[1] = *(const bf16x8*)(q1 + 32);
    }

    f32x4 o[4][2] = {};    // [dt][g]: O^T[d=dt*16+quad*4+r][q=g*16+lc]
    f32x4 racc[2] = {};    // denominator: D[m][q] = sum_k P[k][q] (all m equal)
    const s16x4 ones = {0x3F80, 0x3F80, 0x3F80, 0x3F80};   // bf16 1.0 x4

    // prologue: stage tile 0 into buffer 0 (linear dest, swizzled source)
    {
        unsigned short* Ks = KV;
        unsigned short* Vs = KV + 4096;
        load_lds16(Kg + (size_t)sr * HD + kcc * 8, &Ks[tid * 8]);
        load_lds16(Vg + (size_t)sr * SEQ + kcc * 8, &Vs[tid * 8]);
    }

    for (int t0 = 0; t0 < SEQ; t0 += 64) {
        int cur = (t0 >> 6) & 1;
        unsigned short* Ks = KV + cur * 8192;
        unsigned short* Vs = Ks + 4096;
        __syncthreads();   // drains prior gload_lds (compiler vmcnt) + hazard

        if (t0 + 64 < SEQ) {   // stage next tile into other buffer
            unsigned short* Kn = KV + (cur ^ 1) * 8192;
            unsigned short* Vn = Kn + 4096;
            load_lds16(Kg + (size_t)(t0 + 64 + sr) * HD + kcc * 8, &Kn[tid * 8]);
            load_lds16(Vg + (size_t)sr * SEQ + (t0 + 64) + kcc * 8, &Vn[tid * 8]);
        }

        // QK^T + softmax numerator, per kt (keeps sc lifetime short)
        s16x4 pf[4][2];
        __builtin_amdgcn_s_setprio(1);
        #pragma unroll
        for (int kt = 0; kt < 4; kt++) {
            // row = kt*16 + lc -> s(row) = lc7 ^ ((2*kt + lcb) & 7)
            int sk = lc7 ^ ((2 * kt + lcb) & 7);
            f32x4 sA = {}, sB = {};
            #pragma unroll
            for (int ks = 0; ks < 2; ks++) {
                bf16x8 kf = *(const bf16x8*)
                    &Ks[(kt * 16 + lc) * 64 + ((ks * 4 + quad) ^ sk) * 8];
                sA = __builtin_amdgcn_mfma_f32_16x16x32_bf16(kf, qf0[ks], sA, 0, 0, 0);
                sB = __builtin_amdgcn_mfma_f32_16x16x32_bf16(kf, qf1[ks], sB, 0, 0, 0);
            }
            #pragma unroll
            for (int r = 0; r < 4; r++) {
                float pa = __builtin_amdgcn_exp2f(sA[r]);
                float pb = __builtin_amdgcn_exp2f(sB[r]);
                pf[kt][0][r] = (short)f2b(pa);
                pf[kt][1][r] = (short)f2b(pb);
            }
            // denominator on the MFMA pipe (A=ones -> col sums, all rows equal)
            racc[0] = mfma16(ones, pf[kt][0], racc[0]);
            racc[1] = mfma16(ones, pf[kt][1], racc[1]);
        }

        // PV: o[dt][g] += V^T[d][key] * P[key][q]  (K=16, P register-resident)
        #pragma unroll
        for (int dt = 0; dt < 4; dt++) {
            // row = dt*16 + lc -> s(row) = lc7 ^ ((2*dt + lcb) & 7)
            int sv = lc7 ^ ((2 * dt + lcb) & 7);
            #pragma unroll
            for (int kt = 0; kt < 4; kt++) {
                s16x4 vf = *(const s16x4*)
                    &Vs[(dt * 16 + lc) * 64 +
                        ((2 * kt + (quad >> 1)) ^ sv) * 8 + (quad & 1) * 4];
                o[dt][0] = mfma16(vf, pf[kt][0], o[dt][0]);
                o[dt][1] = mfma16(vf, pf[kt][1], o[dt][1]);
            }
        }
        __builtin_amdgcn_s_setprio(0);
    }

    // denominator: racc[g][r] identical for all r and all quads
    float inv0 = 1.0f / racc[0][0];
    float inv1 = 1.0f / racc[1][0];

    // direct stores: row q = qt*256 + wave*32 + g*16 + lc, cols h*64+dt*16+quad*4
    float* o0 = out + ((size_t)b * SEQ + qt * 256 + wave * 32 + lc) * DIM
                + h * HD + quad * 4;
    float* o1 = o0 + (size_t)16 * DIM;
    #pragma unroll
    for (int dt = 0; dt < 4; dt++) {
        f32x4 s0 = o[dt][0]; s0 *= inv0;
        f32x4 s1 = o[dt][1]; s1 *= inv1;
        *(f32x4*)&o0[dt * 16] = s0;
        *(f32x4*)&o1[dt * 16] = s1;
    }
}

// ---------------------------------------------------------------------------
extern "C" void kernel_launch(void* const* d_in, const int* in_sizes, int n_in,
                              void* d_out, int out_size, void* d_ws, size_t ws_size,
                              hipStream_t stream) {
    (void)in_sizes; (void)n_in; (void)out_size; (void)ws_size;
    const float* x  = (const float*)d_in[0];
    const float* Wq = (const float*)d_in[1];
    const float* bq = (const float*)d_in[2];
    const float* Wk = (const float*)d_in[3];
    const float* bk = (const float*)d_in[4];
    const float* Wv = (const float*)d_in[5];
    const float* bv = (const float*)d_in[6];

    char* ws = (char*)d_ws;
    unsigned short* Wt = (unsigned short*)ws;                             // 6 MB
    unsigned short* Qb = (unsigned short*)(ws + (size_t)6 * 1024 * 1024);
    unsigned short* Kb = Qb + (size_t)BATCH * NH * SEQ * HD;
    unsigned short* Vb = Kb + (size_t)BATCH * NH * SEQ * HD;
    unsigned short* xb = (unsigned short*)d_out;  // scratch; attn overwrites

    cvt_x_k<<<dim3(4096), dim3(256), 0, stream>>>(x, xb);
    transpose_w_k<<<dim3(32, 32, 3), dim3(32, 8), 0, stream>>>(Wq, Wk, Wv, Wt);
    qkv_gemm_k<<<dim3(768), dim3(512), 0, stream>>>(xb, Wt, bq, bk, bv, Qb, Kb, Vb);
    attn_k<<<dim3(512), dim3(512), 0, stream>>>(Qb, Kb, Vb, (float*)d_out);
}

// Round 9
// 239.752 us; speedup vs baseline: 1.2271x; 1.0117x over previous
//
#include <hip/hip_runtime.h>
#include <hip/hip_bf16.h>

// MultiheadAttention: x[4,2048,1024] fp32 -> out fp32. Internal bf16 MFMA.
// R21: attn_k rebuilt on 32x32x16 MFMA (full-rate; the K16 16x16x16_1k used
// for PV/racc runs at HALF FLOP-rate - R20's MfmaUtil 53.5% matches the
// half-rate model, 59% predicted). Per wave-tile MFMA 272 -> 161 cyc:
//   QK: D[key32][q32], A=K-frag (LDS b128), B=Q-frag (global), 8 mfma.
//   P redistribution for PV B-frags: 4 v_permlane32_swap_b32 per key-block
//   (keys 4-7 of each q live in the lane+-32 partner; swap(W0,W2)/swap(W1,W3)
//   builds a K16 B-frag IN PLACE). No LDS, no bpermute.
//   PV: o^T[d32][q32], A=V^T-frag (LDS b128), 8 mfma. racc: A=ones, 4 mfma.
// Staging/s(row)-swizzle/XCD banding/double-buffer unchanged from R20.
// qkv_gemm_k/cvt/transpose unchanged (R20, XCD-panel clustering).

#define DIM  1024
#define SEQ  2048
#define BATCH 4
#define NH   16
#define HD   64

typedef __bf16 bf16x8 __attribute__((ext_vector_type(8)));
typedef short  s16x4  __attribute__((ext_vector_type(4)));
typedef float  f32x4  __attribute__((ext_vector_type(4)));
typedef float  f32x16 __attribute__((ext_vector_type(16)));
typedef unsigned int uint4v __attribute__((ext_vector_type(4)));

static __device__ __forceinline__ f32x16 mfma32(bf16x8 a, bf16x8 b, f32x16 c) {
    return __builtin_amdgcn_mfma_f32_32x32x16_bf16(a, b, c, 0, 0, 0);
}

static __device__ __forceinline__ unsigned short f2b(float f) {
    __bf16 h = (__bf16)f;                      // RNE convert
    return __builtin_bit_cast(unsigned short, h);
}

static __device__ __forceinline__ void load_lds16(const unsigned short* g,
                                                  unsigned short* l) {
    __builtin_amdgcn_global_load_lds(
        (const __attribute__((address_space(1))) void*)g,
        (__attribute__((address_space(3))) void*)l, 16, 0, 0);
}

// ---------------------------------------------------------------------------
// Kernel A: x fp32 -> bf16. 8,388,608 elems -> 4096 blocks.
// ---------------------------------------------------------------------------
__global__ __launch_bounds__(256) void cvt_x_k(const float* __restrict__ x,
                                               unsigned short* __restrict__ xb) {
    size_t i = ((size_t)blockIdx.x * 256 + threadIdx.x) * 8;
    const f32x4* s = (const f32x4*)(x + i);
    f32x4 a0 = s[0], a1 = s[1];
    bf16x8 v;
    for (int j = 0; j < 4; j++) { v[j] = (__bf16)a0[j]; v[4 + j] = (__bf16)a1[j]; }
    *(bf16x8*)(xb + i) = v;
}

// ---------------------------------------------------------------------------
// Kernel 0: Wt[n][k] = bf16(W[k][n]) for z = 0,1,2 (Wq,Wk,Wv). fp32 input.
// ---------------------------------------------------------------------------
__global__ void transpose_w_k(const float* __restrict__ Wq,
                              const float* __restrict__ Wk,
                              const float* __restrict__ Wv,
                              unsigned short* __restrict__ Wt) {
    __shared__ unsigned short t[32][33];
    int z = blockIdx.z;
    const float* W = (z == 0) ? Wq : (z == 1) ? Wk : Wv;
    unsigned short* o = Wt + (size_t)z * DIM * DIM;
    int tx = threadIdx.x;
    int n0 = blockIdx.x * 32, k0 = blockIdx.y * 32;
    for (int j = threadIdx.y; j < 32; j += 8)
        t[j][tx] = f2b(W[(size_t)(k0 + j) * DIM + n0 + tx]);
    __syncthreads();
    for (int j = threadIdx.y; j < 32; j += 8)
        o[(size_t)(n0 + j) * DIM + k0 + tx] = t[tx][j];
}

// ---------------------------------------------------------------------------
// Kernel 1: fused QKV projection (R20 verbatim). 1D grid 768, 512 thr.
// 256x128 tile, BK=64. global_load_lds + XOR swizzle chunk^=(row&7).
// XCD-panel clustering: bid&7 = XCD; 24 blocks sharing an A-panel per XCD.
// ---------------------------------------------------------------------------
__global__ __launch_bounds__(512) void qkv_gemm_k(
    const unsigned short* __restrict__ xb,
    const unsigned short* __restrict__ WtBase,
    const float* __restrict__ bq,
    const float* __restrict__ bk,
    const float* __restrict__ bv,
    unsigned short* __restrict__ Qo,
    unsigned short* __restrict__ Ko,
    unsigned short* __restrict__ Vto) {
    __shared__ __align__(16) unsigned short As[256 * 64];   // 32 KB, NO pad
    __shared__ __align__(16) unsigned short Bs[128 * 64];   // 16 KB
    int tid = threadIdx.x, wave = tid >> 6, lane = tid & 63;
    int quad = lane >> 4, lc = lane & 15;
    // XCD-panel decode
    int bid = blockIdx.x;
    int xcd = bid & 7, slot = bid >> 3;
    int pp = slot / 24, i = slot - pp * 24;
    int p = pp * 8 + xcd;
    int z = i >> 3, nx = i & 7;
    int m0 = p * 256, n0 = nx * 128;
    const unsigned short* Wt = WtBase + (size_t)z * DIM * DIM;
    int wm = (wave >> 1) * 64, wn = (wave & 1) * 64;
    int swzlo = lc & 7;

    f32x4 acc[4][4] = {};

    for (int k0 = 0; k0 < DIM; k0 += 64) {
        __syncthreads();
        #pragma unroll
        for (int pI = 0; pI < 4; pI++) {
            int c = tid + pI * 512, r = c >> 3, cc = (c & 7) ^ (r & 7);
            load_lds16(xb + (size_t)(m0 + r) * DIM + k0 + cc * 8, &As[c * 8]);
        }
        #pragma unroll
        for (int pI = 0; pI < 2; pI++) {
            int c = tid + pI * 512, r = c >> 3, cc = (c & 7) ^ (r & 7);
            load_lds16(Wt + (size_t)(n0 + r) * DIM + k0 + cc * 8, &Bs[c * 8]);
        }
        __syncthreads();
        #pragma unroll
        for (int kk = 0; kk < 2; kk++) {
            int off = ((kk * 4 + quad) ^ swzlo) * 8;
            bf16x8 af[4], bfr[4];
            for (int mt = 0; mt < 4; mt++)
                af[mt] = *(const bf16x8*)&As[(wm + mt * 16 + lc) * 64 + off];
            for (int nt = 0; nt < 4; nt++)
                bfr[nt] = *(const bf16x8*)&Bs[(wn + nt * 16 + lc) * 64 + off];
            for (int mt = 0; mt < 4; mt++)
                for (int nt = 0; nt < 4; nt++)
                    acc[mt][nt] = __builtin_amdgcn_mfma_f32_16x16x32_bf16(
                        af[mt], bfr[nt], acc[mt][nt], 0, 0, 0);
        }
    }

    const float* bias = (z == 0) ? bq : (z == 1) ? bk : bv;
    float scale = (z == 0) ? 0.18033688011112042f : 1.0f;  // (1/8)*log2(e)

    if (z != 2) {
        for (int nt = 0; nt < 4; nt++) {
            int n = n0 + wn + nt * 16 + lc;
            float bvl = bias[n];
            int h = n >> 6, d = n & 63;
            for (int mt = 0; mt < 4; mt++) {
                for (int r = 0; r < 4; r++) {
                    int m = m0 + wm + mt * 16 + quad * 4 + r;
                    int b = m >> 11, s = m & 2047;
                    unsigned short ub = f2b((acc[mt][nt][r] + bvl) * scale);
                    if (z == 0)
                        Qo[((size_t)(b * NH + h) * SEQ + s) * HD + d] = ub;
                    else
                        Ko[((size_t)(b * NH + h) * SEQ + s) * HD + d] = ub;
                }
            }
        }
    } else {
        // V^T: per-wave LDS transpose (16 m x 64 n slices), coalesced stores.
        __syncthreads();
        unsigned short* T = As + wave * 1024;
        int h = (n0 + wn) >> 6;
        int d = lane;
        for (int mt = 0; mt < 4; mt++) {
            for (int nt = 0; nt < 4; nt++) {
                int n = n0 + wn + nt * 16 + lc;
                float bvl = bias[n];
                s16x4 v4;
                for (int r = 0; r < 4; r++)
                    v4[r] = (short)f2b(acc[mt][nt][r] + bvl);
                *(s16x4*)&T[(nt * 16 + lc) * 16 + quad * 4] = v4;
            }
            int s_base = m0 + wm + mt * 16;
            int b = s_base >> 11, sl = s_base & 2047;
            unsigned short* dst =
                Vto + ((size_t)(b * NH + h) * HD + d) * SEQ + sl;
            uint4v t0 = *(const uint4v*)&T[d * 16];
            uint4v t1 = *(const uint4v*)&T[d * 16 + 8];
            *(uint4v*)&dst[0] = t0;
            *(uint4v*)&dst[8] = t1;
        }
    }
}

// ---------------------------------------------------------------------------
// Kernel 2: flash attention (R21, 32x32x16 MFMA). 512 blocks 1-D, 512 thr.
// Block = 256 q; wave owns 32 q (q = wave*32 + lane&31). XCD-banded grid.
// K/V double-buffered LDS 64x64 each; swizzle s(row)=(row^(row>>3))&7.
// QK: D[key][q] = K x Q (8 mfma32). P->B-frag via 4 permlane32_swap/key-block.
// PV: o^T[d][q] = V^T x P (8 mfma32). Denominator: A=ones (4 mfma32).
// ---------------------------------------------------------------------------
__global__ __launch_bounds__(512) void attn_k(
    const unsigned short* __restrict__ Q,
    const unsigned short* __restrict__ K,
    const unsigned short* __restrict__ Vt,
    float* __restrict__ out) {
    // 2 buffers x (K 64x64 + V^T 64x64) shorts = 2 x 16 KB
    __shared__ __align__(16) unsigned short KV[2 * 8192];

    int tid = threadIdx.x, wave = tid >> 6, lane = tid & 63;
    int l31 = lane & 31, hi = lane >> 5;
    // XCD-banded decode: bijective bid -> (bh, qt); 512 blocks, 8 qt per bh
    int bid = blockIdx.x;
    int j = bid >> 3;
    int bh = (bid & 7) * 8 + (j >> 3);
    int qt = j & 7;
    int b = bh >> 4, h = bh & 15;
    const unsigned short* Qg = Q + ((size_t)bh * SEQ + qt * 256) * HD;
    const unsigned short* Kg = K + (size_t)bh * SEQ * HD;
    const unsigned short* Vg = Vt + (size_t)bh * HD * SEQ;

    // staging coords: 512 threads cover one 64x8-chunk tile exactly.
    int sr = tid >> 3, scc = tid & 7;
    int kcc = scc ^ ((sr ^ (sr >> 3)) & 7);

    // Q fragments (B-frag): B[k=d][n=q]: q = wave*32+l31, d = ds*16 + hi*8 + j
    bf16x8 qf[4];
    {
        const unsigned short* q0 = Qg + (size_t)(wave * 32 + l31) * HD + hi * 8;
        #pragma unroll
        for (int ds_ = 0; ds_ < 4; ds_++)
            qf[ds_] = *(const bf16x8*)(q0 + ds_ * 16);
    }

    f32x16 o[2] = {};     // [db]: O^T[d=db*32+row32][q=l31]
    f32x16 racc = {};     // denominator (all 16 rows identical)
    bf16x8 ones8;
    #pragma unroll
    for (int t = 0; t < 8; t++) ones8[t] = (__bf16)1.0f;

    // row-swizzle terms for this lane's MFMA A-frag reads (row = base + l31)
    int swzK0 = ((l31 ^ (l31 >> 3)) & 7);           // rows 0..31
    int r32 = 32 + l31;
    int swzK1 = ((r32 ^ (r32 >> 3)) & 7);           // rows 32..63

    // prologue: stage tile 0 into buffer 0 (linear dest, swizzled source)
    {
        unsigned short* Ks = KV;
        unsigned short* Vs = KV + 4096;
        load_lds16(Kg + (size_t)sr * HD + kcc * 8, &Ks[tid * 8]);
        load_lds16(Vg + (size_t)sr * SEQ + kcc * 8, &Vs[tid * 8]);
    }

    for (int t0 = 0; t0 < SEQ; t0 += 64) {
        int cur = (t0 >> 6) & 1;
        unsigned short* Ks = KV + cur * 8192;
        unsigned short* Vs = Ks + 4096;
        __syncthreads();   // drains prior gload_lds (compiler vmcnt) + hazard

        if (t0 + 64 < SEQ) {   // stage next tile into other buffer
            unsigned short* Kn = KV + (cur ^ 1) * 8192;
            unsigned short* Vn = Kn + 4096;
            load_lds16(Kg + (size_t)(t0 + 64 + sr) * HD + kcc * 8, &Kn[tid * 8]);
            load_lds16(Vg + (size_t)sr * SEQ + (t0 + 64) + kcc * 8, &Vn[tid * 8]);
        }

        __builtin_amdgcn_s_setprio(1);
        #pragma unroll
        for (int kb = 0; kb < 2; kb++) {
            // ---- QK^T: D[key = kb*32 + row32][q = l31], K over d (4 x 16)
            int krow = kb * 32 + l31;
            int ksw = (kb == 0) ? swzK0 : swzK1;
            f32x16 sc = {};
            #pragma unroll
            for (int ds_ = 0; ds_ < 4; ds_++) {
                bf16x8 kfrag = *(const bf16x8*)
                    &Ks[krow * 64 + ((ds_ * 2 + hi) ^ ksw) * 8];
                sc = mfma32(kfrag, qf[ds_], sc);
            }
            // ---- softmax numerator: p = exp2(sc), pack key-pairs as bf16x2
            unsigned int W[8];
            #pragma unroll
            for (int rr = 0; rr < 8; rr++) {
                float p0 = __builtin_amdgcn_exp2f(sc[2 * rr]);
                float p1 = __builtin_amdgcn_exp2f(sc[2 * rr + 1]);
                W[rr] = ((unsigned)f2b(p1) << 16) | (unsigned)f2b(p0);
            }
            // ---- P redistribution: half-swap with lane+-32 partner.
            // After swap(a,b): a' = {a.lo, b.lo}, b' = {a.hi, b.hi}.
            asm volatile("v_permlane32_swap_b32 %0, %1"
                         : "+v"(W[0]), "+v"(W[2]));
            asm volatile("v_permlane32_swap_b32 %0, %1"
                         : "+v"(W[1]), "+v"(W[3]));
            asm volatile("v_permlane32_swap_b32 %0, %1"
                         : "+v"(W[4]), "+v"(W[6]));
            asm volatile("v_permlane32_swap_b32 %0, %1"
                         : "+v"(W[5]), "+v"(W[7]));
            // B-frags: keys kb*32 + 0..15 (fA), kb*32 + 16..31 (fB);
            // lane holds keys hi*8 + j as required by B[k][n] of 32x32x16.
            bf16x8 fA = __builtin_bit_cast(bf16x8,
                            (uint4v){W[0], W[1], W[2], W[3]});
            bf16x8 fB = __builtin_bit_cast(bf16x8,
                            (uint4v){W[4], W[5], W[6], W[7]});
            // ---- denominator on MFMA pipe (A = ones)
            racc = mfma32(ones8, fA, racc);
            racc = mfma32(ones8, fB, racc);
            // ---- PV: o[db] += V^T-frag x P-frag  (K=16 per mfma)
            #pragma unroll
            for (int db = 0; db < 2; db++) {
                int vrow = db * 32 + l31;
                int vsw = (db == 0) ? swzK0 : swzK1;
                bf16x8 v0 = *(const bf16x8*)
                    &Vs[vrow * 64 + ((kb * 4 + hi) ^ vsw) * 8];
                bf16x8 v1 = *(const bf16x8*)
                    &Vs[vrow * 64 + ((kb * 4 + 2 + hi) ^ vsw) * 8];
                o[db] = mfma32(v0, fA, o[db]);
                o[db] = mfma32(v1, fB, o[db]);
            }
        }
        __builtin_amdgcn_s_setprio(0);
    }

    // denominator: all 16 racc rows identical; racc[0] = full sum for q=l31
    float inv = 1.0f / racc[0];

    // stores: row q = qt*256 + wave*32 + l31; d = db*32 + 8*rr + 4*hi + {0..3}
    float* orow = out + ((size_t)b * SEQ + qt * 256 + wave * 32 + l31) * DIM
                  + h * HD + hi * 4;
    #pragma unroll
    for (int db = 0; db < 2; db++) {
        #pragma unroll
        for (int rr = 0; rr < 4; rr++) {
            f32x4 s = { o[db][4 * rr], o[db][4 * rr + 1],
                        o[db][4 * rr + 2], o[db][4 * rr + 3] };
            s *= inv;
            *(f32x4*)&orow[db * 32 + rr * 8] = s;
        }
    }
}

// ---------------------------------------------------------------------------
extern "C" void kernel_launch(void* const* d_in, const int* in_sizes, int n_in,
                              void* d_out, int out_size, void* d_ws, size_t ws_size,
                              hipStream_t stream) {
    (void)in_sizes; (void)n_in; (void)out_size; (void)ws_size;
    const float* x  = (const float*)d_in[0];
    const float* Wq = (const float*)d_in[1];
    const float* bq = (const float*)d_in[2];
    const float* Wk = (const float*)d_in[3];
    const float* bk = (const float*)d_in[4];
    const float* Wv = (const float*)d_in[5];
    const float* bv = (const float*)d_in[6];

    char* ws = (char*)d_ws;
    unsigned short* Wt = (unsigned short*)ws;                             // 6 MB
    unsigned short* Qb = (unsigned short*)(ws + (size_t)6 * 1024 * 1024);
    unsigned short* Kb = Qb + (size_t)BATCH * NH * SEQ * HD;
    unsigned short* Vb = Kb + (size_t)BATCH * NH * SEQ * HD;
    unsigned short* xb = (unsigned short*)d_out;  // scratch; attn overwrites

    cvt_x_k<<<dim3(4096), dim3(256), 0, stream>>>(x, xb);
    transpose_w_k<<<dim3(32, 32, 3), dim3(32, 8), 0, stream>>>(Wq, Wk, Wv, Wt);
    qkv_gemm_k<<<dim3(768), dim3(512), 0, stream>>>(xb, Wt, bq, bk, bv, Qb, Kb, Vb);
    attn_k<<<dim3(512), dim3(512), 0, stream>>>(Qb, Kb, Vb, (float*)d_out);
}

// Round 10
// 237.107 us; speedup vs baseline: 1.2408x; 1.0112x over previous
//
#include <hip/hip_runtime.h>
#include <hip/hip_bf16.h>

// MultiheadAttention: x[4,2048,1024] fp32 -> out fp32. Internal bf16 MFMA.
// R22: three changes on R21 (239.8 us; attn 86.1, zero LDS conflicts).
//  attn_k: KVBLK 64->128 (2 key-blocks per barrier round): barriers 32->16,
//   per-iteration fixed VALU halves. LDS 2x32KB buffers (64KB), 2 blocks/CU.
//   s8(row) swizzle has period 64 -> K rows 0..127 reuse it; V 16-chunk index
//   swizzles only low 3 bits (the bank-relevant part) -> R21's zero-conflict
//   bank pattern preserved exactly.
//  attn_k: P-pair pack via <2 x bf16> vector init (LLVM emits
//   v_cvt_pk_bf16_f32; 1 op vs cvt+cvt+shl+or). No inline asm (m240).
//  prep_k: cvt_x + transpose_w merged into one launch (block-range split) -
//   one less launch gap, the two memory-bound passes overlap.
// qkv_gemm_k unchanged (R20, XCD-panel clustering).

#define DIM  1024
#define SEQ  2048
#define BATCH 4
#define NH   16
#define HD   64

typedef __bf16 bf16x8 __attribute__((ext_vector_type(8)));
typedef __bf16 bf16x2 __attribute__((ext_vector_type(2)));
typedef short  s16x4  __attribute__((ext_vector_type(4)));
typedef float  f32x4  __attribute__((ext_vector_type(4)));
typedef float  f32x16 __attribute__((ext_vector_type(16)));
typedef unsigned int uint4v __attribute__((ext_vector_type(4)));

static __device__ __forceinline__ f32x16 mfma32(bf16x8 a, bf16x8 b, f32x16 c) {
    return __builtin_amdgcn_mfma_f32_32x32x16_bf16(a, b, c, 0, 0, 0);
}

static __device__ __forceinline__ unsigned short f2b(float f) {
    __bf16 h = (__bf16)f;                      // RNE convert
    return __builtin_bit_cast(unsigned short, h);
}

static __device__ __forceinline__ void load_lds16(const unsigned short* g,
                                                  unsigned short* l) {
    __builtin_amdgcn_global_load_lds(
        (const __attribute__((address_space(1))) void*)g,
        (__attribute__((address_space(3))) void*)l, 16, 0, 0);
}

// ---------------------------------------------------------------------------
// Kernel P: merged prep. blocks 0..4095: x fp32 -> bf16 (8 elems/thread).
// blocks 4096..7167: Wt[n][k] = bf16(W[k][n]) tile transpose (32x32, 3 z).
// ---------------------------------------------------------------------------
__global__ __launch_bounds__(256) void prep_k(
    const float* __restrict__ x, unsigned short* __restrict__ xb,
    const float* __restrict__ Wq, const float* __restrict__ Wk,
    const float* __restrict__ Wv, unsigned short* __restrict__ Wt) {
    __shared__ unsigned short t[32][33];
    int bid = blockIdx.x, tid = threadIdx.x;
    if (bid < 4096) {
        size_t i = ((size_t)bid * 256 + tid) * 8;
        const f32x4* s = (const f32x4*)(x + i);
        f32x4 a0 = s[0], a1 = s[1];
        bf16x8 v;
        for (int j = 0; j < 4; j++) { v[j] = (__bf16)a0[j]; v[4 + j] = (__bf16)a1[j]; }
        *(bf16x8*)(xb + i) = v;
    } else {
        int r = bid - 4096;                    // 0..3071
        int z = r >> 10;                       // 1024 tiles per z
        int by = (r >> 5) & 31, bx = r & 31;
        const float* W = (z == 0) ? Wq : (z == 1) ? Wk : Wv;
        unsigned short* o = Wt + (size_t)z * DIM * DIM;
        int tx = tid & 31, ty = tid >> 5;
        int n0 = bx * 32, k0 = by * 32;
        for (int j = ty; j < 32; j += 8)
            t[j][tx] = f2b(W[(size_t)(k0 + j) * DIM + n0 + tx]);
        __syncthreads();
        for (int j = ty; j < 32; j += 8)
            o[(size_t)(n0 + j) * DIM + k0 + tx] = t[tx][j];
    }
}

// ---------------------------------------------------------------------------
// Kernel 1: fused QKV projection (R20 verbatim). 1D grid 768, 512 thr.
// 256x128 tile, BK=64. global_load_lds + XOR swizzle chunk^=(row&7).
// XCD-panel clustering: bid&7 = XCD; 24 blocks sharing an A-panel per XCD.
// ---------------------------------------------------------------------------
__global__ __launch_bounds__(512) void qkv_gemm_k(
    const unsigned short* __restrict__ xb,
    const unsigned short* __restrict__ WtBase,
    const float* __restrict__ bq,
    const float* __restrict__ bk,
    const float* __restrict__ bv,
    unsigned short* __restrict__ Qo,
    unsigned short* __restrict__ Ko,
    unsigned short* __restrict__ Vto) {
    __shared__ __align__(16) unsigned short As[256 * 64];   // 32 KB, NO pad
    __shared__ __align__(16) unsigned short Bs[128 * 64];   // 16 KB
    int tid = threadIdx.x, wave = tid >> 6, lane = tid & 63;
    int quad = lane >> 4, lc = lane & 15;
    // XCD-panel decode
    int bid = blockIdx.x;
    int xcd = bid & 7, slot = bid >> 3;
    int pp = slot / 24, i = slot - pp * 24;
    int p = pp * 8 + xcd;
    int z = i >> 3, nx = i & 7;
    int m0 = p * 256, n0 = nx * 128;
    const unsigned short* Wt = WtBase + (size_t)z * DIM * DIM;
    int wm = (wave >> 1) * 64, wn = (wave & 1) * 64;
    int swzlo = lc & 7;

    f32x4 acc[4][4] = {};

    for (int k0 = 0; k0 < DIM; k0 += 64) {
        __syncthreads();
        #pragma unroll
        for (int pI = 0; pI < 4; pI++) {
            int c = tid + pI * 512, r = c >> 3, cc = (c & 7) ^ (r & 7);
            load_lds16(xb + (size_t)(m0 + r) * DIM + k0 + cc * 8, &As[c * 8]);
        }
        #pragma unroll
        for (int pI = 0; pI < 2; pI++) {
            int c = tid + pI * 512, r = c >> 3, cc = (c & 7) ^ (r & 7);
            load_lds16(Wt + (size_t)(n0 + r) * DIM + k0 + cc * 8, &Bs[c * 8]);
        }
        __syncthreads();
        #pragma unroll
        for (int kk = 0; kk < 2; kk++) {
            int off = ((kk * 4 + quad) ^ swzlo) * 8;
            bf16x8 af[4], bfr[4];
            for (int mt = 0; mt < 4; mt++)
                af[mt] = *(const bf16x8*)&As[(wm + mt * 16 + lc) * 64 + off];
            for (int nt = 0; nt < 4; nt++)
                bfr[nt] = *(const bf16x8*)&Bs[(wn + nt * 16 + lc) * 64 + off];
            for (int mt = 0; mt < 4; mt++)
                for (int nt = 0; nt < 4; nt++)
                    acc[mt][nt] = __builtin_amdgcn_mfma_f32_16x16x32_bf16(
                        af[mt], bfr[nt], acc[mt][nt], 0, 0, 0);
        }
    }

    const float* bias = (z == 0) ? bq : (z == 1) ? bk : bv;
    float scale = (z == 0) ? 0.18033688011112042f : 1.0f;  // (1/8)*log2(e)

    if (z != 2) {
        for (int nt = 0; nt < 4; nt++) {
            int n = n0 + wn + nt * 16 + lc;
            float bvl = bias[n];
            int h = n >> 6, d = n & 63;
            for (int mt = 0; mt < 4; mt++) {
                for (int r = 0; r < 4; r++) {
                    int m = m0 + wm + mt * 16 + quad * 4 + r;
                    int b = m >> 11, s = m & 2047;
                    unsigned short ub = f2b((acc[mt][nt][r] + bvl) * scale);
                    if (z == 0)
                        Qo[((size_t)(b * NH + h) * SEQ + s) * HD + d] = ub;
                    else
                        Ko[((size_t)(b * NH + h) * SEQ + s) * HD + d] = ub;
                }
            }
        }
    } else {
        // V^T: per-wave LDS transpose (16 m x 64 n slices), coalesced stores.
        __syncthreads();
        unsigned short* T = As + wave * 1024;
        int h = (n0 + wn) >> 6;
        int d = lane;
        for (int mt = 0; mt < 4; mt++) {
            for (int nt = 0; nt < 4; nt++) {
                int n = n0 + wn + nt * 16 + lc;
                float bvl = bias[n];
                s16x4 v4;
                for (int r = 0; r < 4; r++)
                    v4[r] = (short)f2b(acc[mt][nt][r] + bvl);
                *(s16x4*)&T[(nt * 16 + lc) * 16 + quad * 4] = v4;
            }
            int s_base = m0 + wm + mt * 16;
            int b = s_base >> 11, sl = s_base & 2047;
            unsigned short* dst =
                Vto + ((size_t)(b * NH + h) * HD + d) * SEQ + sl;
            uint4v t0 = *(const uint4v*)&T[d * 16];
            uint4v t1 = *(const uint4v*)&T[d * 16 + 8];
            *(uint4v*)&dst[0] = t0;
            *(uint4v*)&dst[8] = t1;
        }
    }
}

// ---------------------------------------------------------------------------
// Kernel 2: flash attention (R22, KVBLK=128). 512 blocks 1-D, 512 thr.
// Block = 256 q; wave owns 32 q (q = wave*32 + l31). XCD-banded grid.
// Per iteration: stage 128-key tile (K[128][64] + V^T[64][128], 64KB dbuf),
// one barrier, 4 key-blocks of {QK 32x32 MFMA, exp2+pk-pack, permlane
// redistribution, racc, PV}. s8(row) swizzle (period 64) zero-conflict.
// ---------------------------------------------------------------------------
__global__ __launch_bounds__(512) void attn_k(
    const unsigned short* __restrict__ Q,
    const unsigned short* __restrict__ K,
    const unsigned short* __restrict__ Vt,
    float* __restrict__ out) {
    // 2 buffers x (K 128x64 + V^T 64x128) shorts = 2 x 32 KB
    __shared__ __align__(16) unsigned short KV[2 * 16384];

    int tid = threadIdx.x, wave = tid >> 6, lane = tid & 63;
    int l31 = lane & 31, hi = lane >> 5;
    // XCD-banded decode: bijective bid -> (bh, qt); 512 blocks, 8 qt per bh
    int bid = blockIdx.x;
    int j = bid >> 3;
    int bh = (bid & 7) * 8 + (j >> 3);
    int qt = j & 7;
    int b = bh >> 4, h = bh & 15;
    const unsigned short* Qg = Q + ((size_t)bh * SEQ + qt * 256) * HD;
    const unsigned short* Kg = K + (size_t)bh * SEQ * HD;
    const unsigned short* Vg = Vt + (size_t)bh * HD * SEQ;

    // staging coords (512 thr, 2 passes p=0,1 cover 1024 slots per array)
    // K: slot -> row = slot>>3 (0..127), c8 = slot&7; src chunk = c8 ^ s8(row)
    // V: slot -> row = slot>>4 (0..63), c16 = slot&15;
    //    src chunk = (c16&8) | ((c16&7) ^ s8(row))   (bank-relevant low 3 bits)
    int kr0 = tid >> 3, kc0 = tid & 7;
    int ks0 = kc0 ^ ((kr0 ^ (kr0 >> 3)) & 7);
    int kr1 = (tid + 512) >> 3, kc1 = tid & 7;
    int ks1 = kc1 ^ ((kr1 ^ (kr1 >> 3)) & 7);
    int vr0 = tid >> 4, vc0 = tid & 15;
    int vs0 = (vc0 & 8) | ((vc0 & 7) ^ ((vr0 ^ (vr0 >> 3)) & 7));
    int vr1 = (tid + 512) >> 4, vc1 = tid & 15;
    int vs1 = (vc1 & 8) | ((vc1 & 7) ^ ((vr1 ^ (vr1 >> 3)) & 7));

    // Q fragments (B-frag): B[k=d][n=q]: q = wave*32+l31, d = ds*16 + hi*8 + j
    bf16x8 qf[4];
    {
        const unsigned short* q0 = Qg + (size_t)(wave * 32 + l31) * HD + hi * 8;
        #pragma unroll
        for (int ds_ = 0; ds_ < 4; ds_++)
            qf[ds_] = *(const bf16x8*)(q0 + ds_ * 16);
    }

    f32x16 o[2] = {};     // [db]: O^T[d=db*32+row32][q=l31]
    f32x16 racc = {};     // denominator (all 16 rows identical)
    bf16x8 ones8;
    #pragma unroll
    for (int t = 0; t < 8; t++) ones8[t] = (__bf16)1.0f;

    // row-swizzle for MFMA A-frag reads (rows base+l31; s8 period 64)
    int swzK0 = ((l31 ^ (l31 >> 3)) & 7);           // rows 0..31 (mod 64)
    int r32 = 32 + l31;
    int swzK1 = ((r32 ^ (r32 >> 3)) & 7);           // rows 32..63 (mod 64)

    // prologue: stage tile 0 into buffer 0 (linear dest, swizzled source)
    {
        unsigned short* Ks = KV;
        unsigned short* Vs = KV + 8192;
        load_lds16(Kg + (size_t)kr0 * HD + ks0 * 8, &Ks[tid * 8]);
        load_lds16(Kg + (size_t)kr1 * HD + ks1 * 8, &Ks[(tid + 512) * 8]);
        load_lds16(Vg + (size_t)vr0 * SEQ + vs0 * 8, &Vs[tid * 8]);
        load_lds16(Vg + (size_t)vr1 * SEQ + vs1 * 8, &Vs[(tid + 512) * 8]);
    }

    for (int t0 = 0; t0 < SEQ; t0 += 128) {
        int cur = (t0 >> 7) & 1;
        unsigned short* Ks = KV + cur * 16384;
        unsigned short* Vs = Ks + 8192;
        __syncthreads();   // drains prior gload_lds (compiler vmcnt) + hazard

        if (t0 + 128 < SEQ) {   // stage next 128-key tile into other buffer
            unsigned short* Kn = KV + (cur ^ 1) * 16384;
            unsigned short* Vn = Kn + 8192;
            load_lds16(Kg + (size_t)(t0 + 128 + kr0) * HD + ks0 * 8,
                       &Kn[tid * 8]);
            load_lds16(Kg + (size_t)(t0 + 128 + kr1) * HD + ks1 * 8,
                       &Kn[(tid + 512) * 8]);
            load_lds16(Vg + (size_t)vr0 * SEQ + (t0 + 128) + vs0 * 8,
                       &Vn[tid * 8]);
            load_lds16(Vg + (size_t)vr1 * SEQ + (t0 + 128) + vs1 * 8,
                       &Vn[(tid + 512) * 8]);
        }

        __builtin_amdgcn_s_setprio(1);
        #pragma unroll
        for (int kb = 0; kb < 4; kb++) {
            // ---- QK^T: D[key = kb*32 + row32][q = l31], K over d (4 x 16)
            int krow = kb * 32 + l31;
            int ksw = (kb & 1) ? swzK1 : swzK0;
            f32x16 sc = {};
            #pragma unroll
            for (int ds_ = 0; ds_ < 4; ds_++) {
                bf16x8 kfrag = *(const bf16x8*)
                    &Ks[krow * 64 + ((ds_ * 2 + hi) ^ ksw) * 8];
                sc = mfma32(kfrag, qf[ds_], sc);
            }
            // ---- softmax numerator: p = exp2(sc), pack pairs via cvt_pk
            unsigned int W[8];
            #pragma unroll
            for (int rr = 0; rr < 8; rr++) {
                float p0 = __builtin_amdgcn_exp2f(sc[2 * rr]);
                float p1 = __builtin_amdgcn_exp2f(sc[2 * rr + 1]);
                bf16x2 pk; pk[0] = (__bf16)p0; pk[1] = (__bf16)p1;
                W[rr] = __builtin_bit_cast(unsigned int, pk);
            }
            // ---- P redistribution: half-swap with lane+-32 partner.
            asm volatile("v_permlane32_swap_b32 %0, %1"
                         : "+v"(W[0]), "+v"(W[2]));
            asm volatile("v_permlane32_swap_b32 %0, %1"
                         : "+v"(W[1]), "+v"(W[3]));
            asm volatile("v_permlane32_swap_b32 %0, %1"
                         : "+v"(W[4]), "+v"(W[6]));
            asm volatile("v_permlane32_swap_b32 %0, %1"
                         : "+v"(W[5]), "+v"(W[7]));
            bf16x8 fA = __builtin_bit_cast(bf16x8,
                            (uint4v){W[0], W[1], W[2], W[3]});
            bf16x8 fB = __builtin_bit_cast(bf16x8,
                            (uint4v){W[4], W[5], W[6], W[7]});
            // ---- denominator on MFMA pipe (A = ones)
            racc = mfma32(ones8, fA, racc);
            racc = mfma32(ones8, fB, racc);
            // ---- PV: o[db] += V^T-frag x P-frag  (K=16 per mfma)
            #pragma unroll
            for (int db = 0; db < 2; db++) {
                int vrow = db * 32 + l31;
                int vsw = (db == 0) ? swzK0 : swzK1;
                int rawA = kb * 4 + hi, rawB = kb * 4 + 2 + hi;
                int cA = (rawA & 8) | ((rawA & 7) ^ vsw);
                int cB = (rawB & 8) | ((rawB & 7) ^ vsw);
                bf16x8 v0 = *(const bf16x8*)&Vs[vrow * 128 + cA * 8];
                bf16x8 v1 = *(const bf16x8*)&Vs[vrow * 128 + cB * 8];
                o[db] = mfma32(v0, fA, o[db]);
                o[db] = mfma32(v1, fB, o[db]);
            }
        }
        __builtin_amdgcn_s_setprio(0);
    }

    // denominator: all 16 racc rows identical; racc[0] = full sum for q=l31
    float inv = 1.0f / racc[0];

    // stores: row q = qt*256 + wave*32 + l31; d = db*32 + 8*rr + 4*hi + {0..3}
    float* orow = out + ((size_t)b * SEQ + qt * 256 + wave * 32 + l31) * DIM
                  + h * HD + hi * 4;
    #pragma unroll
    for (int db = 0; db < 2; db++) {
        #pragma unroll
        for (int rr = 0; rr < 4; rr++) {
            f32x4 s = { o[db][4 * rr], o[db][4 * rr + 1],
                        o[db][4 * rr + 2], o[db][4 * rr + 3] };
            s *= inv;
            *(f32x4*)&orow[db * 32 + rr * 8] = s;
        }
    }
}

// ---------------------------------------------------------------------------
extern "C" void kernel_launch(void* const* d_in, const int* in_sizes, int n_in,
                              void* d_out, int out_size, void* d_ws, size_t ws_size,
                              hipStream_t stream) {
    (void)in_sizes; (void)n_in; (void)out_size; (void)ws_size;
    const float* x  = (const float*)d_in[0];
    const float* Wq = (const float*)d_in[1];
    const float* bq = (const float*)d_in[2];
    const float* Wk = (const float*)d_in[3];
    const float* bk = (const float*)d_in[4];
    const float* Wv = (const float*)d_in[5];
    const float* bv = (const float*)d_in[6];

    char* ws = (char*)d_ws;
    unsigned short* Wt = (unsigned short*)ws;                             // 6 MB
    unsigned short* Qb = (unsigned short*)(ws + (size_t)6 * 1024 * 1024);
    unsigned short* Kb = Qb + (size_t)BATCH * NH * SEQ * HD;
    unsigned short* Vb = Kb + (size_t)BATCH * NH * SEQ * HD;
    unsigned short* xb = (unsigned short*)d_out;  // scratch; attn overwrites

    prep_k<<<dim3(7168), dim3(256), 0, stream>>>(x, xb, Wq, Wk, Wv, Wt);
    qkv_gemm_k<<<dim3(768), dim3(512), 0, stream>>>(xb, Wt, bq, bk, bv, Qb, Kb, Vb);
    attn_k<<<dim3(512), dim3(512), 0, stream>>>(Qb, Kb, Vb, (float*)d_out);
}